// Round 12
// baseline (335.460 us; speedup 1.0000x reference)
//
#include <hip/hip_runtime.h>
#include <math.h>

#define NFEAT  128
#define HC     256     // HEADS*NHID
#define HEADS  8
#define NHID   32
#define NCLASS 40

typedef unsigned int  uint;
typedef unsigned short ushort;
typedef unsigned char uchar;

typedef __attribute__((ext_vector_type(8))) short bf16x8;
typedef __attribute__((ext_vector_type(4))) float f32x4;

union U8 { uint4 u; bf16x8 v; };

// bf16 helpers (RNE pack, cheap unpack)
__device__ __forceinline__ uint f2bf1(float f) {
    uint b = __float_as_uint(f);
    b += 0x7FFFu + ((b >> 16) & 1u);
    return b >> 16;
}
__device__ __forceinline__ uint packbf(float lo, float hi) {
    return f2bf1(lo) | (f2bf1(hi) << 16);
}
__device__ __forceinline__ float bflo(uint u) { return __uint_as_float(u << 16); }
__device__ __forceinline__ float bfhi(uint u) { return __uint_as_float(u & 0xFFFF0000u); }

// fp8 e4m3 (OCP) via HW converts
__device__ __forceinline__ uchar f2fp8(float v) {
    return (uchar)(__builtin_amdgcn_cvt_pk_fp8_f32(v, v, 0, false) & 0xFF);
}

// ---------------- CSR build (dst-sorted, shared by both layers) ----------------

#define HU 4
__global__ void k_hist(const int* __restrict__ dst, int E, int* deg) {
    int tid = blockIdx.x * 256 + threadIdx.x;
    int stride = gridDim.x * 256;
#pragma unroll
    for (int j = 0; j < HU; ++j) {
        int i = tid + j * stride;
        if (i < E) atomicAdd(&deg[dst[i]], 1);
    }
}

// per-block sums of (deg+1)  [+1 = self-loop]
__global__ void k_blocksum(const int* __restrict__ deg, int n, int* bsum) {
    __shared__ int lds[256];
    int b = blockIdx.x, t = threadIdx.x;
    int i = b * 256 + t;
    lds[t] = (i < n) ? deg[i] + 1 : 0;
    __syncthreads();
    for (int off = 128; off >= 1; off >>= 1) {
        if (t < off) lds[t] += lds[t + off];
        __syncthreads();
    }
    if (t == 0) bsum[b] = lds[0];
}

// fused: per-block parallel reduce of bsum[0..b) + local scan -> ptr/cur
__global__ void k_mkptr(const int* __restrict__ deg, const int* __restrict__ bsum,
                        int n, int* ptr, int* cur) {
    __shared__ int lds[256];
    __shared__ int base_s;
    int b = blockIdx.x, t = threadIdx.x;
    int p = 0;
    for (int i = t; i < b; i += 256) p += bsum[i];
    lds[t] = p;
    __syncthreads();
    for (int off = 128; off >= 1; off >>= 1) {
        if (t < off) lds[t] += lds[t + off];
        __syncthreads();
    }
    if (t == 0) base_s = lds[0];
    __syncthreads();
    int i = b * 256 + t;
    int v = (i < n) ? deg[i] + 1 : 0;   // +1 self-loop
    lds[t] = v;
    __syncthreads();
    for (int off = 1; off < 256; off <<= 1) {
        int u = (t >= off) ? lds[t - off] : 0;
        __syncthreads();
        lds[t] += u;
        __syncthreads();
    }
    int excl = lds[t] - v + base_s;
    if (i < n) {
        ptr[i] = excl;
        cur[i] = excl;
        if (i == n - 1) ptr[n] = excl + v;
    }
}

// scatter, 8 independent atomic chains per thread (latency hiding)
#define SU 8
__global__ void k_scatter(const int* __restrict__ srcE, const int* __restrict__ dstE,
                          int E, int n, int* cur, int* __restrict__ srcs) {
    int tid = blockIdx.x * 256 + threadIdx.x;
    int stride = gridDim.x * 256;
    int tot = E + n;
    int s[SU], d[SU], pos[SU];
    bool v[SU];
#pragma unroll
    for (int j = 0; j < SU; ++j) {
        int i = tid + j * stride;
        v[j] = i < tot;
        s[j] = 0; d[j] = 0;
        if (v[j]) {
            if (i < E) { s[j] = srcE[i]; d[j] = dstE[i]; }
            else       { s[j] = d[j] = i - E; }          // self-loop
        }
    }
#pragma unroll
    for (int j = 0; j < SU; ++j)
        if (v[j]) pos[j] = atomicAdd(&cur[d[j]], 1);
#pragma unroll
    for (int j = 0; j < SU; ++j)
        if (v[j]) srcs[pos[j]] = s[j];
}

// ---------------- MFMA prep: W1 -> B frags (bf16), tiles 0..15 = W1 cols,
// tile 16 = attention tile: col c<8 -> Was[k,h=c], col c>=8 -> Wad[k,h=c-8].
__global__ __launch_bounds__(256)
void k_prepw(const float* __restrict__ W1,
             const float* __restrict__ attS, const float* __restrict__ attD,
             ushort* __restrict__ Wb) {
    int g = blockIdx.x * 256 + threadIdx.x;        // 17*256 threads
    int lane = g & 63;
    int step = (g >> 6) & 3;
    int tile = g >> 8;
    int k0 = step * 32 + (lane >> 4) * 8;
    float f[8];
    if (tile < 16) {
        int ncol = tile * 16 + (lane & 15);
#pragma unroll
        for (int j = 0; j < 8; ++j) f[j] = W1[(size_t)(k0 + j) * HC + ncol];
    } else {
        int cc = lane & 15;
        int h = cc & 7;
        const float* av = (cc < 8) ? attS : attD;
#pragma unroll
        for (int j = 0; j < 8; ++j) {
            const float* wr = W1 + (size_t)(k0 + j) * HC + h * 32;
            float s = 0.f;
#pragma unroll
            for (int c = 0; c < 32; ++c) s += wr[c] * av[h * 32 + c];
            f[j] = s;
        }
    }
    uint4 o;
    o.x = packbf(f[0], f[1]);
    o.y = packbf(f[2], f[3]);
    o.z = packbf(f[4], f[5]);
    o.w = packbf(f[6], f[7]);
    *(uint4*)(Wb + (size_t)g * 8) = o;
}

// ---------------- GEMM1 (MFMA bf16): h1 = x @ W1, fp8 h1 out ----------------
__global__ __launch_bounds__(256)
void k_gemm1(const float* __restrict__ x,
             const ushort* __restrict__ Wb,
             int n, uchar* __restrict__ h1f8,
             float* __restrict__ a1x) {
    __shared__ uint Xs[64 * 68];        // 17.4 KB; aliased as Cs[64][272]B later
    int t = threadIdx.x;
    int lane = t & 63;
    int w = t >> 6;
    int n0 = blockIdx.x * 64;

#pragma unroll
    for (int j = 0; j < 8; ++j) {
        int f4 = t + j * 256;
        int node = f4 >> 5;
        int k4 = (f4 & 31) * 4;
        int gn = n0 + node;
        float4 v = make_float4(0.f, 0.f, 0.f, 0.f);
        if (gn < n) v = *(const float4*)(x + (size_t)gn * NFEAT + k4);
        uint2 pk;
        pk.x = packbf(v.x, v.y);
        pk.y = packbf(v.z, v.w);
        *(uint2*)(Xs + node * 68 + (k4 >> 1)) = pk;
    }
    __syncthreads();

    int m = lane & 15;
    int q4 = (lane >> 4) * 4;
    bf16x8 Af[4];
#pragma unroll
    for (int ks = 0; ks < 4; ++ks) {
        U8 a;
        a.u = *(const uint4*)(Xs + (w * 16 + m) * 68 + ks * 16 + q4);
        Af[ks] = a.v;
    }
    __syncthreads();

    f32x4 acc[17];
#pragma unroll
    for (int i = 0; i < 17; ++i) acc[i] = (f32x4){0.f, 0.f, 0.f, 0.f};

    const bf16x8* Bf = (const bf16x8*)Wb;
#pragma unroll
    for (int ks = 0; ks < 4; ++ks) {
#pragma unroll
        for (int nt = 0; nt < 17; ++nt) {
            bf16x8 bv = Bf[(size_t)(nt * 4 + ks) * 64 + lane];
            acc[nt] = __builtin_amdgcn_mfma_f32_16x16x32_bf16(Af[ks], bv, acc[nt], 0, 0, 0);
        }
    }

    int cc = lane & 15;
    int r0 = (lane >> 4) * 4;

    // attention tile (nt=16): col cc -> a1x[gn*16+cc] (0..7 src heads, 8..15 dst)
#pragma unroll
    for (int r = 0; r < 4; ++r) {
        int gn = n0 + w * 16 + r0 + r;
        if (gn < n) a1x[(size_t)gn * 16 + cc] = acc[16][r];
    }

    uchar* CsB = (uchar*)Xs;
#pragma unroll
    for (int nt = 0; nt < 16; ++nt) {
#pragma unroll
        for (int r = 0; r < 4; ++r)
            CsB[(w * 16 + r0 + r) * 272 + nt * 16 + cc] = f2fp8(acc[nt][r]);
    }
    __syncthreads();

    int node_local = t >> 2;
    int q = t & 3;
    int gn = n0 + node_local;
    if (gn < n) {
        const uchar* crow = CsB + node_local * 272 + q * 64;
        uchar* hp = h1f8 + (size_t)gn * HC + q * 64;
#pragma unroll
        for (int i = 0; i < 4; ++i)
            *(uint4*)(hp + i * 16) = *(const uint4*)(crow + i * 16);
    }
}

// ---------------- Layer-1 aggregation: wave/dst, segment-hoisted softmax ----
// Pass A: lane=(edge j=lane&7, head h=lane>>3) computes e for 8 edges x 8 heads
// at once (8x less redundant VALU), LDS stash; 3-shuffle max per head.
// Pass A2: p=exp(e-m) in LDS + 3-shuffle sum. Gather loop: p (LDS broadcast)
// * fp8 h1 -- NO exp/fmax/rescale in the hot loop.
#define SEGE 128
__global__ __launch_bounds__(256)
void k_agg1(const uint* __restrict__ h1u, const float* __restrict__ a1x,
            const float* __restrict__ b1,
            const int* __restrict__ ptr, const int* __restrict__ srcs,
            int n, ushort* __restrict__ hgb) {
    __shared__ float esh[4][SEGE * 8];   // 16 KB, per-wave private
    int w = threadIdx.x >> 6;
    int wid = blockIdx.x * 4 + w;
    if (wid >= n) return;
    int lane = threadIdx.x & 63;
    int h = lane >> 3;
    int j = lane & 7;
    float* es = esh[w];

    float adn = a1x[(size_t)wid * 16 + 8 + h];
    int beg = __builtin_amdgcn_readfirstlane(ptr[wid]);
    int end = __builtin_amdgcn_readfirstlane(ptr[wid + 1]);

    float m_run = -INFINITY, s_run = 0.f;
    float4 acc = make_float4(0.f, 0.f, 0.f, 0.f);

    for (int seg = beg; seg < end; seg += SEGE) {
        int seg_n = min(SEGE, end - seg);
        // ---- pass A: e values, lane-specialized (j,h) ----
        float mloc = -INFINITY;
        for (int c = 0; c < seg_n; c += 8) {
            int li = c + j;
            bool v = li < seg_n;
            int sn = srcs[v ? seg + li : seg];
            float e = -INFINITY;
            if (v) {
                float a = a1x[(size_t)sn * 16 + h] + adn;
                e = (a > 0.f) ? a : 0.2f * a;
            }
            es[li * 8 + h] = e;
            mloc = fmaxf(mloc, e);
        }
        float m_seg = mloc;
        m_seg = fmaxf(m_seg, __shfl_xor(m_seg, 1, 64));
        m_seg = fmaxf(m_seg, __shfl_xor(m_seg, 2, 64));
        m_seg = fmaxf(m_seg, __shfl_xor(m_seg, 4, 64));
        float m_new = fmaxf(m_run, m_seg);
        float corr = __expf(m_run - m_new);
        // ---- pass A2: p = exp(e - m_new), per-head sum ----
        float sloc = 0.f;
        for (int c = 0; c < seg_n; c += 8) {
            int li = c + j;
            float e = es[li * 8 + h];
            float p = __expf(e - m_new);
            es[li * 8 + h] = p;
            sloc += p;
        }
        sloc += __shfl_xor(sloc, 1, 64);
        sloc += __shfl_xor(sloc, 2, 64);
        sloc += __shfl_xor(sloc, 4, 64);
        s_run = s_run * corr + sloc;
        acc.x *= corr; acc.y *= corr; acc.z *= corr; acc.w *= corr;
        // ---- gather: p broadcast * fp8 h1, 8-wide MLP ----
        int i = 0;
        for (; i + 8 <= seg_n; i += 8) {
            int sn[8];
            float p[8];
            uint hv[8];
#pragma unroll
            for (int jj = 0; jj < 8; ++jj) sn[jj] = __builtin_amdgcn_readfirstlane(srcs[seg + i + jj]);
#pragma unroll
            for (int jj = 0; jj < 8; ++jj) p[jj] = es[(i + jj) * 8 + h];
#pragma unroll
            for (int jj = 0; jj < 8; ++jj) hv[jj] = h1u[(size_t)sn[jj] * 64 + lane];
#pragma unroll
            for (int jj = 0; jj < 8; ++jj) {
                auto lo = __builtin_amdgcn_cvt_pk_f32_fp8((int)hv[jj], false);
                auto hi = __builtin_amdgcn_cvt_pk_f32_fp8((int)hv[jj], true);
                acc.x += p[jj] * lo[0];
                acc.y += p[jj] * lo[1];
                acc.z += p[jj] * hi[0];
                acc.w += p[jj] * hi[1];
            }
        }
        for (; i < seg_n; ++i) {
            int sn = __builtin_amdgcn_readfirstlane(srcs[seg + i]);
            float p = es[i * 8 + h];
            uint hv = h1u[(size_t)sn * 64 + lane];
            auto lo = __builtin_amdgcn_cvt_pk_f32_fp8((int)hv, false);
            auto hi = __builtin_amdgcn_cvt_pk_f32_fp8((int)hv, true);
            acc.x += p * lo[0];
            acc.y += p * lo[1];
            acc.z += p * hi[0];
            acc.w += p * hi[1];
        }
        m_run = m_new;
    }

    float inv = 1.f / (s_run + 1e-16f);
    float4 bv = *(const float4*)(b1 + lane * 4);
    float4 o;
    o.x = acc.x * inv + bv.x;
    o.y = acc.y * inv + bv.y;
    o.z = acc.z * inv + bv.z;
    o.w = acc.w * inv + bv.w;
    o.x = (o.x > 0.f) ? o.x : (__expf(o.x) - 1.f);
    o.y = (o.y > 0.f) ? o.y : (__expf(o.y) - 1.f);
    o.z = (o.z > 0.f) ? o.z : (__expf(o.z) - 1.f);
    o.w = (o.w > 0.f) ? o.w : (__expf(o.w) - 1.f);
    uint2 ov;
    ov.x = packbf(o.x, o.y);
    ov.y = packbf(o.z, o.w);
    *(uint2*)(hgb + (size_t)wid * HC + lane * 4) = ov;
}

// ---------------- GEMM2: h2 = hg @ W2  [N,256]x[256,40], bf16 in/out ----------------
__global__ __launch_bounds__(256)
void k_gemm2(const ushort* __restrict__ hgb, const float* __restrict__ W2,
             const float* __restrict__ a2sw, const float* __restrict__ a2dw,
             int n, ushort* __restrict__ h2b,
             float* __restrict__ a2s, float* __restrict__ a2d) {
    __shared__ uint Xs[128 * 65];       // 33.3 KB, [k2][node]
    __shared__ float Ps[4][64];
    __shared__ float Pd[4][64];
    int t = threadIdx.x;
    int lane = t & 63;
    int w = t >> 6;
    int n0 = blockIdx.x * 64;

#pragma unroll
    for (int j = 0; j < 8; ++j) {
        int g = t + j * 256;
        int node = g >> 5;
        int k2b = (g & 31) * 4;
        int gn = n0 + node;
        uint4 v = make_uint4(0u, 0u, 0u, 0u);
        if (gn < n) v = *(const uint4*)(hgb + (size_t)gn * HC + k2b * 2);
        Xs[(k2b + 0) * 65 + node] = v.x;
        Xs[(k2b + 1) * 65 + node] = v.y;
        Xs[(k2b + 2) * 65 + node] = v.z;
        Xs[(k2b + 3) * 65 + node] = v.w;
    }
    __syncthreads();

    int wu = __builtin_amdgcn_readfirstlane(w);
    const float* Wc = W2 + wu * 10;

    float acc[10];
#pragma unroll
    for (int c = 0; c < 10; ++c) acc[c] = 0.f;

#pragma unroll 2
    for (int k2 = 0; k2 < 128; ++k2) {
        uint xp = Xs[k2 * 65 + lane];
        float x0 = bflo(xp), x1 = bfhi(xp);
        const float* Wr0 = Wc + (size_t)(2 * k2) * NCLASS;
        const float* Wr1 = Wr0 + NCLASS;
#pragma unroll
        for (int c = 0; c < 10; ++c) {
            acc[c] += x0 * Wr0[c] + x1 * Wr1[c];
        }
    }

    int gn = n0 + lane;
    float as = 0.f, ad = 0.f;
#pragma unroll
    for (int c = 0; c < 10; ++c) {
        as += acc[c] * a2sw[wu * 10 + c];
        ad += acc[c] * a2dw[wu * 10 + c];
    }
    Ps[w][lane] = as;
    Pd[w][lane] = ad;
    if (gn < n) {
        uint* hp = (uint*)(h2b + (size_t)gn * NCLASS + wu * 10);
#pragma unroll
        for (int q = 0; q < 5; ++q)
            hp[q] = packbf(acc[q * 2], acc[q * 2 + 1]);
    }
    __syncthreads();
    if (w == 0 && gn < n) {
        a2s[gn] = Ps[0][lane] + Ps[1][lane] + Ps[2][lane] + Ps[3][lane];
        a2d[gn] = Pd[0][lane] + Pd[1][lane] + Pd[2][lane] + Pd[3][lane];
    }
}

// ---------------- Layer-2 aggregation, segment-hoisted softmax + log_softmax ----
#define SEGE2 256
__global__ __launch_bounds__(256)
void k_agg2(const ushort* __restrict__ h2b, const float* __restrict__ a2s,
            const float* __restrict__ a2d, const float* __restrict__ b2,
            const int* __restrict__ ptr, const int* __restrict__ srcs,
            int n, float* __restrict__ out) {
    __shared__ float esh[4][SEGE2];      // 4 KB, per-wave private
    int w = threadIdx.x >> 6;
    int wid = blockIdx.x * 4 + w;
    if (wid >= n) return;
    int lane = threadIdx.x & 63;
    bool live = lane < NCLASS;
    int col = live ? lane : 0;
    float* es = esh[w];

    float adn = a2d[wid];
    int beg = __builtin_amdgcn_readfirstlane(ptr[wid]);
    int end = __builtin_amdgcn_readfirstlane(ptr[wid + 1]);

    float m_run = -INFINITY, s_run = 0.f, acc = 0.f;

    for (int seg = beg; seg < end; seg += SEGE2) {
        int seg_n = min(SEGE2, end - seg);
        // pass A: e per edge, 64 edges/chunk
        float mloc = -INFINITY;
        for (int c = 0; c < seg_n; c += 64) {
            int li = c + lane;
            bool v = li < seg_n;
            int sn = srcs[v ? seg + li : seg];
            float e = -INFINITY;
            if (v) {
                float a = a2s[sn] + adn;
                e = (a > 0.f) ? a : 0.2f * a;
            }
            es[li] = e;
            mloc = fmaxf(mloc, e);
        }
        float m_seg = mloc;
#pragma unroll
        for (int msk = 1; msk < 64; msk <<= 1)
            m_seg = fmaxf(m_seg, __shfl_xor(m_seg, msk, 64));
        float m_new = fmaxf(m_run, m_seg);
        float corr = __expf(m_run - m_new);
        // pass A2: p + sum
        float sloc = 0.f;
        for (int c = 0; c < seg_n; c += 64) {
            int li = c + lane;
            float e = es[li];
            float p = __expf(e - m_new);
            es[li] = p;
            sloc += p;
        }
#pragma unroll
        for (int msk = 1; msk < 64; msk <<= 1)
            sloc += __shfl_xor(sloc, msk, 64);
        s_run = s_run * corr + sloc;
        acc *= corr;
        // gather
        int i = 0;
        for (; i + 8 <= seg_n; i += 8) {
            int sn[8];
            float p[8], hv[8];
#pragma unroll
            for (int jj = 0; jj < 8; ++jj) sn[jj] = __builtin_amdgcn_readfirstlane(srcs[seg + i + jj]);
#pragma unroll
            for (int jj = 0; jj < 8; ++jj) p[jj] = es[i + jj];
#pragma unroll
            for (int jj = 0; jj < 8; ++jj)
                hv[jj] = __uint_as_float((uint)h2b[(size_t)sn[jj] * NCLASS + col] << 16);
#pragma unroll
            for (int jj = 0; jj < 8; ++jj) acc += p[jj] * hv[jj];
        }
        for (; i < seg_n; ++i) {
            int sn = __builtin_amdgcn_readfirstlane(srcs[seg + i]);
            float p = es[i];
            float hv = __uint_as_float((uint)h2b[(size_t)sn * NCLASS + col] << 16);
            acc += p * hv;
        }
        m_run = m_new;
    }

    float val0 = acc / (s_run + 1e-16f) + (live ? b2[lane] : 0.f);
    float vmax = live ? val0 : -INFINITY;
#pragma unroll
    for (int msk = 1; msk < 64; msk <<= 1) vmax = fmaxf(vmax, __shfl_xor(vmax, msk, 64));
    float ex = live ? __expf(val0 - vmax) : 0.f;
#pragma unroll
    for (int msk = 1; msk < 64; msk <<= 1) ex += __shfl_xor(ex, msk, 64);
    float res = val0 - vmax - __logf(ex);
    if (live) out[(size_t)wid * NCLASS + lane] = res;
}

// ---------------- launch ----------------
extern "C" void kernel_launch(void* const* d_in, const int* in_sizes, int n_in,
                              void* d_out, int out_size, void* d_ws, size_t ws_size,
                              hipStream_t stream) {
    const float* x    = (const float*)d_in[0];
    const int*   ei   = (const int*)  d_in[1];
    const float* W1   = (const float*)d_in[2];
    const float* attS = (const float*)d_in[3];
    const float* attD = (const float*)d_in[4];
    const float* b1   = (const float*)d_in[5];
    const float* W2   = (const float*)d_in[6];
    const float* a2sw = (const float*)d_in[7];
    const float* a2dw = (const float*)d_in[8];
    const float* b2   = (const float*)d_in[9];

    int n = in_sizes[0] / NFEAT;
    int E = in_sizes[1] / 2;
    const int* srcE = ei;
    const int* dstE = ei + E;
    int nb = (n + 255) / 256;
    int mblocks = (n + 63) / 64;

    char* p = (char*)d_ws;
    auto alloc = [&](size_t bytes) {
        char* r = p;
        p += (bytes + 255) & ~(size_t)255;
        return r;
    };
    uchar*  h1f8 = (uchar*)alloc((size_t)n * HC);
    ushort* hgb  = (ushort*)alloc((size_t)n * HC * 2);
    ushort* h2b  = (ushort*)alloc((size_t)n * NCLASS * 2);
    ushort* Wb   = (ushort*)alloc((size_t)17 * 4 * 64 * 8 * 2);
    float* a1x = (float*)alloc((size_t)n * 16 * 4);
    float* a2s = (float*)alloc((size_t)n * 4);
    float* a2d = (float*)alloc((size_t)n * 4);
    int* deg  = (int*)alloc((size_t)n * 4);
    int* bsum = (int*)alloc((size_t)nb * 4);
    int* ptr  = (int*)alloc((size_t)(n + 1) * 4);
    int* cur  = (int*)alloc((size_t)n * 4);
    int* srcs = (int*)alloc((size_t)(E + n) * 4);

    int tot = E + n;
    hipMemsetAsync(deg, 0, (size_t)n * 4, stream);
    k_hist<<<(E + 256 * HU - 1) / (256 * HU), 256, 0, stream>>>(dstE, E, deg);
    k_blocksum<<<nb, 256, 0, stream>>>(deg, n, bsum);
    k_mkptr<<<nb, 256, 0, stream>>>(deg, bsum, n, ptr, cur);
    k_scatter<<<(tot + 256 * SU - 1) / (256 * SU), 256, 0, stream>>>(srcE, dstE, E, n, cur, srcs);

    k_prepw<<<17, 256, 0, stream>>>(W1, attS, attD, Wb);
    k_gemm1<<<mblocks, 256, 0, stream>>>(x, Wb, n, h1f8, a1x);
    k_agg1<<<(n + 3) / 4, 256, 0, stream>>>((const uint*)h1f8, a1x, b1,
                                            ptr, srcs, n, hgb);
    k_gemm2<<<(n + 63) / 64, 256, 0, stream>>>(hgb, W2, a2sw, a2dw, n, h2b, a2s, a2d);
    k_agg2<<<(n + 3) / 4, 256, 0, stream>>>(h2b, a2s, a2d, b2, ptr, srcs, n, (float*)d_out);
}

// Round 13
// 334.862 us; speedup vs baseline: 1.0018x; 1.0018x over previous
//
#include <hip/hip_runtime.h>
#include <math.h>

#define NFEAT  128
#define HC     256     // HEADS*NHID
#define HEADS  8
#define NHID   32
#define NCLASS 40

typedef unsigned int  uint;
typedef unsigned short ushort;
typedef unsigned char uchar;

typedef __attribute__((ext_vector_type(8))) short bf16x8;
typedef __attribute__((ext_vector_type(4))) float f32x4;

union U8 { uint4 u; bf16x8 v; };

// bf16 helpers (RNE pack, cheap unpack)
__device__ __forceinline__ uint f2bf1(float f) {
    uint b = __float_as_uint(f);
    b += 0x7FFFu + ((b >> 16) & 1u);
    return b >> 16;
}
__device__ __forceinline__ uint packbf(float lo, float hi) {
    return f2bf1(lo) | (f2bf1(hi) << 16);
}
__device__ __forceinline__ float bflo(uint u) { return __uint_as_float(u << 16); }
__device__ __forceinline__ float bfhi(uint u) { return __uint_as_float(u & 0xFFFF0000u); }

// fp8 e4m3 (OCP) via HW converts
__device__ __forceinline__ uchar f2fp8(float v) {
    return (uchar)(__builtin_amdgcn_cvt_pk_fp8_f32(v, v, 0, false) & 0xFF);
}

// ---------------- CSR build (dst-sorted, shared by both layers) ----------------

#define HU 4
__global__ void k_hist(const int* __restrict__ dst, int E, int* deg) {
    int tid = blockIdx.x * 256 + threadIdx.x;
    int stride = gridDim.x * 256;
#pragma unroll
    for (int j = 0; j < HU; ++j) {
        int i = tid + j * stride;
        if (i < E) atomicAdd(&deg[dst[i]], 1);
    }
}

// per-block sums of (deg+1)  [+1 = self-loop]
__global__ void k_blocksum(const int* __restrict__ deg, int n, int* bsum) {
    __shared__ int lds[256];
    int b = blockIdx.x, t = threadIdx.x;
    int i = b * 256 + t;
    lds[t] = (i < n) ? deg[i] + 1 : 0;
    __syncthreads();
    for (int off = 128; off >= 1; off >>= 1) {
        if (t < off) lds[t] += lds[t + off];
        __syncthreads();
    }
    if (t == 0) bsum[b] = lds[0];
}

// fused: per-block parallel reduce of bsum[0..b) + local scan -> ptr/cur
__global__ void k_mkptr(const int* __restrict__ deg, const int* __restrict__ bsum,
                        int n, int* ptr, int* cur) {
    __shared__ int lds[256];
    __shared__ int base_s;
    int b = blockIdx.x, t = threadIdx.x;
    int p = 0;
    for (int i = t; i < b; i += 256) p += bsum[i];
    lds[t] = p;
    __syncthreads();
    for (int off = 128; off >= 1; off >>= 1) {
        if (t < off) lds[t] += lds[t + off];
        __syncthreads();
    }
    if (t == 0) base_s = lds[0];
    __syncthreads();
    int i = b * 256 + t;
    int v = (i < n) ? deg[i] + 1 : 0;   // +1 self-loop
    lds[t] = v;
    __syncthreads();
    for (int off = 1; off < 256; off <<= 1) {
        int u = (t >= off) ? lds[t - off] : 0;
        __syncthreads();
        lds[t] += u;
        __syncthreads();
    }
    int excl = lds[t] - v + base_s;
    if (i < n) {
        ptr[i] = excl;
        cur[i] = excl;
        if (i == n - 1) ptr[n] = excl + v;
    }
}

// scatter, 8 independent atomic chains per thread (latency hiding)
#define SU 8
__global__ void k_scatter(const int* __restrict__ srcE, const int* __restrict__ dstE,
                          int E, int n, int* cur, int* __restrict__ srcs) {
    int tid = blockIdx.x * 256 + threadIdx.x;
    int stride = gridDim.x * 256;
    int tot = E + n;
    int s[SU], d[SU], pos[SU];
    bool v[SU];
#pragma unroll
    for (int j = 0; j < SU; ++j) {
        int i = tid + j * stride;
        v[j] = i < tot;
        s[j] = 0; d[j] = 0;
        if (v[j]) {
            if (i < E) { s[j] = srcE[i]; d[j] = dstE[i]; }
            else       { s[j] = d[j] = i - E; }          // self-loop
        }
    }
#pragma unroll
    for (int j = 0; j < SU; ++j)
        if (v[j]) pos[j] = atomicAdd(&cur[d[j]], 1);
#pragma unroll
    for (int j = 0; j < SU; ++j)
        if (v[j]) srcs[pos[j]] = s[j];
}

// ---------------- MFMA prep: W1 -> B frags (bf16), tiles 0..15 = W1 cols,
// tile 16 = attention tile: col c<8 -> Was[k,h=c], col c>=8 -> Wad[k,h=c-8].
__global__ __launch_bounds__(256)
void k_prepw(const float* __restrict__ W1,
             const float* __restrict__ attS, const float* __restrict__ attD,
             ushort* __restrict__ Wb) {
    int g = blockIdx.x * 256 + threadIdx.x;        // 17*256 threads
    int lane = g & 63;
    int step = (g >> 6) & 3;
    int tile = g >> 8;
    int k0 = step * 32 + (lane >> 4) * 8;
    float f[8];
    if (tile < 16) {
        int ncol = tile * 16 + (lane & 15);
#pragma unroll
        for (int j = 0; j < 8; ++j) f[j] = W1[(size_t)(k0 + j) * HC + ncol];
    } else {
        int cc = lane & 15;
        int h = cc & 7;
        const float* av = (cc < 8) ? attS : attD;
#pragma unroll
        for (int j = 0; j < 8; ++j) {
            const float* wr = W1 + (size_t)(k0 + j) * HC + h * 32;
            float s = 0.f;
#pragma unroll
            for (int c = 0; c < 32; ++c) s += wr[c] * av[h * 32 + c];
            f[j] = s;
        }
    }
    uint4 o;
    o.x = packbf(f[0], f[1]);
    o.y = packbf(f[2], f[3]);
    o.z = packbf(f[4], f[5]);
    o.w = packbf(f[6], f[7]);
    *(uint4*)(Wb + (size_t)g * 8) = o;
}

// ---------------- GEMM1 (MFMA bf16): h1 = x @ W1, fp8 h1 out ----------------
__global__ __launch_bounds__(256)
void k_gemm1(const float* __restrict__ x,
             const ushort* __restrict__ Wb,
             int n, uchar* __restrict__ h1f8,
             float* __restrict__ a1x) {
    __shared__ uint Xs[64 * 68];        // 17.4 KB; aliased as Cs[64][272]B later
    int t = threadIdx.x;
    int lane = t & 63;
    int w = t >> 6;
    int n0 = blockIdx.x * 64;

#pragma unroll
    for (int j = 0; j < 8; ++j) {
        int f4 = t + j * 256;
        int node = f4 >> 5;
        int k4 = (f4 & 31) * 4;
        int gn = n0 + node;
        float4 v = make_float4(0.f, 0.f, 0.f, 0.f);
        if (gn < n) v = *(const float4*)(x + (size_t)gn * NFEAT + k4);
        uint2 pk;
        pk.x = packbf(v.x, v.y);
        pk.y = packbf(v.z, v.w);
        *(uint2*)(Xs + node * 68 + (k4 >> 1)) = pk;
    }
    __syncthreads();

    int m = lane & 15;
    int q4 = (lane >> 4) * 4;
    bf16x8 Af[4];
#pragma unroll
    for (int ks = 0; ks < 4; ++ks) {
        U8 a;
        a.u = *(const uint4*)(Xs + (w * 16 + m) * 68 + ks * 16 + q4);
        Af[ks] = a.v;
    }
    __syncthreads();

    f32x4 acc[17];
#pragma unroll
    for (int i = 0; i < 17; ++i) acc[i] = (f32x4){0.f, 0.f, 0.f, 0.f};

    const bf16x8* Bf = (const bf16x8*)Wb;
#pragma unroll
    for (int ks = 0; ks < 4; ++ks) {
#pragma unroll
        for (int nt = 0; nt < 17; ++nt) {
            bf16x8 bv = Bf[(size_t)(nt * 4 + ks) * 64 + lane];
            acc[nt] = __builtin_amdgcn_mfma_f32_16x16x32_bf16(Af[ks], bv, acc[nt], 0, 0, 0);
        }
    }

    int cc = lane & 15;
    int r0 = (lane >> 4) * 4;

    // attention tile (nt=16): col cc -> a1x[gn*16+cc] (0..7 src heads, 8..15 dst)
#pragma unroll
    for (int r = 0; r < 4; ++r) {
        int gn = n0 + w * 16 + r0 + r;
        if (gn < n) a1x[(size_t)gn * 16 + cc] = acc[16][r];
    }

    uchar* CsB = (uchar*)Xs;
#pragma unroll
    for (int nt = 0; nt < 16; ++nt) {
#pragma unroll
        for (int r = 0; r < 4; ++r)
            CsB[(w * 16 + r0 + r) * 272 + nt * 16 + cc] = f2fp8(acc[nt][r]);
    }
    __syncthreads();

    int node_local = t >> 2;
    int q = t & 3;
    int gn = n0 + node_local;
    if (gn < n) {
        const uchar* crow = CsB + node_local * 272 + q * 64;
        uchar* hp = h1f8 + (size_t)gn * HC + q * 64;
#pragma unroll
        for (int i = 0; i < 4; ++i)
            *(uint4*)(hp + i * 16) = *(const uint4*)(crow + i * 16);
    }
}

// ---------------- Layer-1 aggregation: one wave per dst node, online softmax ----------------
// fp8 h1 gather (256B/edge), 8-wide unroll + masked tail. Range [wbase,wend) so
// the launch can be SPLIT (frees rocprof top-5 slots; agg1 replays were hiding
// the rest of the pipeline since round 8).
__global__ __launch_bounds__(256)
void k_agg1(const uint* __restrict__ h1u, const float* __restrict__ a1x,
            const float* __restrict__ b1,
            const int* __restrict__ ptr, const int* __restrict__ srcs,
            int wbase, int wend, ushort* __restrict__ hgb) {
    int wid = wbase + blockIdx.x * 4 + (threadIdx.x >> 6);
    if (wid >= wend) return;
    int lane = threadIdx.x & 63;
    int h = lane >> 3;
    float adn = a1x[(size_t)wid * 16 + 8 + h];
    int beg = __builtin_amdgcn_readfirstlane(ptr[wid]);
    int end = __builtin_amdgcn_readfirstlane(ptr[wid + 1]);
    float m = -INFINITY, s = 0.f;
    float4 acc = make_float4(0.f, 0.f, 0.f, 0.f);

    int i = beg;
    for (; i + 8 <= end; i += 8) {
        int sn[8];
#pragma unroll
        for (int j = 0; j < 8; ++j) sn[j] = __builtin_amdgcn_readfirstlane(srcs[i + j]);
        float av[8];
        uint hv[8];
#pragma unroll
        for (int j = 0; j < 8; ++j) av[j] = a1x[(size_t)sn[j] * 16 + h];
#pragma unroll
        for (int j = 0; j < 8; ++j)
            hv[j] = h1u[(size_t)sn[j] * 64 + lane];
        float e[8];
#pragma unroll
        for (int j = 0; j < 8; ++j) {
            float a = av[j] + adn;
            e[j] = (a > 0.f) ? a : 0.2f * a;
        }
        float mn = m;
#pragma unroll
        for (int j = 0; j < 8; ++j) mn = fmaxf(mn, e[j]);
        float corr = __expf(m - mn);
        float p[8];
#pragma unroll
        for (int j = 0; j < 8; ++j) p[j] = __expf(e[j] - mn);
        float ps = 0.f;
#pragma unroll
        for (int j = 0; j < 8; ++j) ps += p[j];
        s = s * corr + ps;
        float cx = acc.x * corr, cy = acc.y * corr, cz = acc.z * corr, cw = acc.w * corr;
#pragma unroll
        for (int j = 0; j < 8; ++j) {
            auto lo = __builtin_amdgcn_cvt_pk_f32_fp8((int)hv[j], false);
            auto hi = __builtin_amdgcn_cvt_pk_f32_fp8((int)hv[j], true);
            cx += p[j] * lo[0];
            cy += p[j] * lo[1];
            cz += p[j] * hi[0];
            cw += p[j] * hi[1];
        }
        acc = make_float4(cx, cy, cz, cw);
        m = mn;
    }
    if (i < end) {                       // masked final iteration
        int sn[8];
        bool val[8];
#pragma unroll
        for (int j = 0; j < 8; ++j) {
            int idx = i + j;
            val[j] = idx < end;
            sn[j] = __builtin_amdgcn_readfirstlane(srcs[val[j] ? idx : end - 1]);
        }
        float av[8];
        uint hv[8];
#pragma unroll
        for (int j = 0; j < 8; ++j) av[j] = a1x[(size_t)sn[j] * 16 + h];
#pragma unroll
        for (int j = 0; j < 8; ++j)
            hv[j] = h1u[(size_t)sn[j] * 64 + lane];
        float e[8];
#pragma unroll
        for (int j = 0; j < 8; ++j) {
            float a = av[j] + adn;
            e[j] = val[j] ? ((a > 0.f) ? a : 0.2f * a) : -INFINITY;
        }
        float mn = m;
#pragma unroll
        for (int j = 0; j < 8; ++j) mn = fmaxf(mn, e[j]);
        float corr = __expf(m - mn);
        float p[8];
#pragma unroll
        for (int j = 0; j < 8; ++j) p[j] = __expf(e[j] - mn);
        float ps = 0.f;
#pragma unroll
        for (int j = 0; j < 8; ++j) ps += p[j];
        s = s * corr + ps;
        float cx = acc.x * corr, cy = acc.y * corr, cz = acc.z * corr, cw = acc.w * corr;
#pragma unroll
        for (int j = 0; j < 8; ++j) {
            auto lo = __builtin_amdgcn_cvt_pk_f32_fp8((int)hv[j], false);
            auto hi = __builtin_amdgcn_cvt_pk_f32_fp8((int)hv[j], true);
            cx += p[j] * lo[0];
            cy += p[j] * lo[1];
            cz += p[j] * hi[0];
            cw += p[j] * hi[1];
        }
        acc = make_float4(cx, cy, cz, cw);
        m = mn;
    }

    float inv = 1.f / (s + 1e-16f);
    float4 bv = *(const float4*)(b1 + lane * 4);
    float4 o;
    o.x = acc.x * inv + bv.x;
    o.y = acc.y * inv + bv.y;
    o.z = acc.z * inv + bv.z;
    o.w = acc.w * inv + bv.w;
    o.x = (o.x > 0.f) ? o.x : (__expf(o.x) - 1.f);
    o.y = (o.y > 0.f) ? o.y : (__expf(o.y) - 1.f);
    o.z = (o.z > 0.f) ? o.z : (__expf(o.z) - 1.f);
    o.w = (o.w > 0.f) ? o.w : (__expf(o.w) - 1.f);
    uint2 ov;
    ov.x = packbf(o.x, o.y);
    ov.y = packbf(o.z, o.w);
    *(uint2*)(hgb + (size_t)wid * HC + lane * 4) = ov;
}

// ---------------- GEMM2: h2 = hg @ W2  [N,256]x[256,40], bf16 in/out ----------------
__global__ __launch_bounds__(256)
void k_gemm2(const ushort* __restrict__ hgb, const float* __restrict__ W2,
             const float* __restrict__ a2sw, const float* __restrict__ a2dw,
             int n, ushort* __restrict__ h2b,
             float* __restrict__ a2s, float* __restrict__ a2d) {
    __shared__ uint Xs[128 * 65];       // 33.3 KB, [k2][node]
    __shared__ float Ps[4][64];
    __shared__ float Pd[4][64];
    int t = threadIdx.x;
    int lane = t & 63;
    int w = t >> 6;
    int n0 = blockIdx.x * 64;

#pragma unroll
    for (int j = 0; j < 8; ++j) {
        int g = t + j * 256;
        int node = g >> 5;
        int k2b = (g & 31) * 4;
        int gn = n0 + node;
        uint4 v = make_uint4(0u, 0u, 0u, 0u);
        if (gn < n) v = *(const uint4*)(hgb + (size_t)gn * HC + k2b * 2);
        Xs[(k2b + 0) * 65 + node] = v.x;
        Xs[(k2b + 1) * 65 + node] = v.y;
        Xs[(k2b + 2) * 65 + node] = v.z;
        Xs[(k2b + 3) * 65 + node] = v.w;
    }
    __syncthreads();

    int wu = __builtin_amdgcn_readfirstlane(w);
    const float* Wc = W2 + wu * 10;

    float acc[10];
#pragma unroll
    for (int c = 0; c < 10; ++c) acc[c] = 0.f;

#pragma unroll 2
    for (int k2 = 0; k2 < 128; ++k2) {
        uint xp = Xs[k2 * 65 + lane];
        float x0 = bflo(xp), x1 = bfhi(xp);
        const float* Wr0 = Wc + (size_t)(2 * k2) * NCLASS;
        const float* Wr1 = Wr0 + NCLASS;
#pragma unroll
        for (int c = 0; c < 10; ++c) {
            acc[c] += x0 * Wr0[c] + x1 * Wr1[c];
        }
    }

    int gn = n0 + lane;
    float as = 0.f, ad = 0.f;
#pragma unroll
    for (int c = 0; c < 10; ++c) {
        as += acc[c] * a2sw[wu * 10 + c];
        ad += acc[c] * a2dw[wu * 10 + c];
    }
    Ps[w][lane] = as;
    Pd[w][lane] = ad;
    if (gn < n) {
        uint* hp = (uint*)(h2b + (size_t)gn * NCLASS + wu * 10);
#pragma unroll
        for (int q = 0; q < 5; ++q)
            hp[q] = packbf(acc[q * 2], acc[q * 2 + 1]);
    }
    __syncthreads();
    if (w == 0 && gn < n) {
        a2s[gn] = Ps[0][lane] + Ps[1][lane] + Ps[2][lane] + Ps[3][lane];
        a2d[gn] = Pd[0][lane] + Pd[1][lane] + Pd[2][lane] + Pd[3][lane];
    }
}

// ---------------- Layer-2 aggregation + bias + log_softmax (online softmax) ----
__global__ __launch_bounds__(256)
void k_agg2(const ushort* __restrict__ h2b, const float* __restrict__ a2s,
            const float* __restrict__ a2d, const float* __restrict__ b2,
            const int* __restrict__ ptr, const int* __restrict__ srcs,
            int n, float* __restrict__ out) {
    int wid = blockIdx.x * 4 + (threadIdx.x >> 6);
    if (wid >= n) return;
    int lane = threadIdx.x & 63;
    bool live = lane < NCLASS;
    int col = live ? lane : 0;
    float adn = a2d[wid];
    int beg = __builtin_amdgcn_readfirstlane(ptr[wid]);
    int end = __builtin_amdgcn_readfirstlane(ptr[wid + 1]);
    float m = -INFINITY, s = 0.f, acc = 0.f;

    int i = beg;
    for (; i + 8 <= end; i += 8) {
        int sn[8];
#pragma unroll
        for (int j = 0; j < 8; ++j) sn[j] = __builtin_amdgcn_readfirstlane(srcs[i + j]);
        float av[8];
        float hv[8];
#pragma unroll
        for (int j = 0; j < 8; ++j) av[j] = a2s[sn[j]];
#pragma unroll
        for (int j = 0; j < 8; ++j)
            hv[j] = __uint_as_float((uint)h2b[(size_t)sn[j] * NCLASS + col] << 16);
        float e[8];
#pragma unroll
        for (int j = 0; j < 8; ++j) {
            float a = av[j] + adn;
            e[j] = (a > 0.f) ? a : 0.2f * a;
        }
        float mn = m;
#pragma unroll
        for (int j = 0; j < 8; ++j) mn = fmaxf(mn, e[j]);
        float corr = __expf(m - mn);
        float p[8];
#pragma unroll
        for (int j = 0; j < 8; ++j) p[j] = __expf(e[j] - mn);
        float ps = 0.f, pa = 0.f;
#pragma unroll
        for (int j = 0; j < 8; ++j) { ps += p[j]; pa += p[j] * hv[j]; }
        s = s * corr + ps;
        acc = acc * corr + pa;
        m = mn;
    }
    if (i < end) {
        int sn[8];
        bool val[8];
#pragma unroll
        for (int j = 0; j < 8; ++j) {
            int idx = i + j;
            val[j] = idx < end;
            sn[j] = __builtin_amdgcn_readfirstlane(srcs[val[j] ? idx : end - 1]);
        }
        float av[8];
        float hv[8];
#pragma unroll
        for (int j = 0; j < 8; ++j) av[j] = a2s[sn[j]];
#pragma unroll
        for (int j = 0; j < 8; ++j)
            hv[j] = __uint_as_float((uint)h2b[(size_t)sn[j] * NCLASS + col] << 16);
        float e[8];
#pragma unroll
        for (int j = 0; j < 8; ++j) {
            float a = av[j] + adn;
            e[j] = val[j] ? ((a > 0.f) ? a : 0.2f * a) : -INFINITY;
        }
        float mn = m;
#pragma unroll
        for (int j = 0; j < 8; ++j) mn = fmaxf(mn, e[j]);
        float corr = __expf(m - mn);
        float p[8];
#pragma unroll
        for (int j = 0; j < 8; ++j) p[j] = __expf(e[j] - mn);
        float ps = 0.f, pa = 0.f;
#pragma unroll
        for (int j = 0; j < 8; ++j) { ps += p[j]; pa += p[j] * hv[j]; }
        s = s * corr + ps;
        acc = acc * corr + pa;
        m = mn;
    }

    float val0 = acc / (s + 1e-16f) + (live ? b2[lane] : 0.f);
    float vmax = live ? val0 : -INFINITY;
#pragma unroll
    for (int msk = 1; msk < 64; msk <<= 1) vmax = fmaxf(vmax, __shfl_xor(vmax, msk, 64));
    float ex = live ? __expf(val0 - vmax) : 0.f;
#pragma unroll
    for (int msk = 1; msk < 64; msk <<= 1) ex += __shfl_xor(ex, msk, 64);
    float res = val0 - vmax - __logf(ex);
    if (live) out[(size_t)wid * NCLASS + lane] = res;
}

// ---------------- launch ----------------
extern "C" void kernel_launch(void* const* d_in, const int* in_sizes, int n_in,
                              void* d_out, int out_size, void* d_ws, size_t ws_size,
                              hipStream_t stream) {
    const float* x    = (const float*)d_in[0];
    const int*   ei   = (const int*)  d_in[1];
    const float* W1   = (const float*)d_in[2];
    const float* attS = (const float*)d_in[3];
    const float* attD = (const float*)d_in[4];
    const float* b1   = (const float*)d_in[5];
    const float* W2   = (const float*)d_in[6];
    const float* a2sw = (const float*)d_in[7];
    const float* a2dw = (const float*)d_in[8];
    const float* b2   = (const float*)d_in[9];

    int n = in_sizes[0] / NFEAT;
    int E = in_sizes[1] / 2;
    const int* srcE = ei;
    const int* dstE = ei + E;
    int nb = (n + 255) / 256;
    int mblocks = (n + 63) / 64;

    char* p = (char*)d_ws;
    auto alloc = [&](size_t bytes) {
        char* r = p;
        p += (bytes + 255) & ~(size_t)255;
        return r;
    };
    uchar*  h1f8 = (uchar*)alloc((size_t)n * HC);
    ushort* hgb  = (ushort*)alloc((size_t)n * HC * 2);
    ushort* h2b  = (ushort*)alloc((size_t)n * NCLASS * 2);
    ushort* Wb   = (ushort*)alloc((size_t)17 * 4 * 64 * 8 * 2);
    float* a1x = (float*)alloc((size_t)n * 16 * 4);
    float* a2s = (float*)alloc((size_t)n * 4);
    float* a2d = (float*)alloc((size_t)n * 4);
    int* deg  = (int*)alloc((size_t)n * 4);
    int* bsum = (int*)alloc((size_t)nb * 4);
    int* ptr  = (int*)alloc((size_t)(n + 1) * 4);
    int* cur  = (int*)alloc((size_t)n * 4);
    int* srcs = (int*)alloc((size_t)(E + n) * 4);

    int tot = E + n;
    hipMemsetAsync(deg, 0, (size_t)n * 4, stream);
    k_hist<<<(E + 256 * HU - 1) / (256 * HU), 256, 0, stream>>>(dstE, E, deg);
    k_blocksum<<<nb, 256, 0, stream>>>(deg, n, bsum);
    k_mkptr<<<nb, 256, 0, stream>>>(deg, bsum, n, ptr, cur);
    k_scatter<<<(tot + 256 * SU - 1) / (256 * SU), 256, 0, stream>>>(srcE, dstE, E, n, cur, srcs);

    k_prepw<<<17, 256, 0, stream>>>(W1, attS, attD, Wb);
    k_gemm1<<<mblocks, 256, 0, stream>>>(x, Wb, n, h1f8, a1x);

    // agg1 split into two half-range launches: frees rocprof top-5 slots so the
    // rest of the pipeline's ranking is visible (agg1 is at its ~52us floor).
    int half = (n + 1) / 2;
    k_agg1<<<(half + 3) / 4, 256, 0, stream>>>((const uint*)h1f8, a1x, b1,
                                               ptr, srcs, 0, half, hgb);
    k_agg1<<<(n - half + 3) / 4, 256, 0, stream>>>((const uint*)h1f8, a1x, b1,
                                                   ptr, srcs, half, n, hgb);

    k_gemm2<<<(n + 63) / 64, 256, 0, stream>>>(hgb, W2, a2sw, a2dw, n, h2b, a2s, a2d);
    k_agg2<<<(n + 3) / 4, 256, 0, stream>>>(h2b, a2s, a2d, b2, ptr, srcs, n, (float*)d_out);
}

// Round 14
// 294.916 us; speedup vs baseline: 1.1375x; 1.1354x over previous
//
#include <hip/hip_runtime.h>
#include <math.h>

#define NFEAT  128
#define HC     256     // HEADS*NHID
#define HEADS  8
#define NHID   32
#define NCLASS 40

typedef unsigned int  uint;
typedef unsigned short ushort;
typedef unsigned char uchar;

typedef __attribute__((ext_vector_type(8))) short bf16x8;
typedef __attribute__((ext_vector_type(4))) float f32x4;

union U8 { uint4 u; bf16x8 v; };

// bf16 helpers (RNE pack, cheap unpack)
__device__ __forceinline__ uint f2bf1(float f) {
    uint b = __float_as_uint(f);
    b += 0x7FFFu + ((b >> 16) & 1u);
    return b >> 16;
}
__device__ __forceinline__ uint packbf(float lo, float hi) {
    return f2bf1(lo) | (f2bf1(hi) << 16);
}
__device__ __forceinline__ float bflo(uint u) { return __uint_as_float(u << 16); }
__device__ __forceinline__ float bfhi(uint u) { return __uint_as_float(u & 0xFFFF0000u); }

// fp8 e4m3 (OCP) via HW converts
__device__ __forceinline__ uchar f2fp8(float v) {
    return (uchar)(__builtin_amdgcn_cvt_pk_fp8_f32(v, v, 0, false) & 0xFF);
}
__device__ __forceinline__ float fp8tof(uint byte) {
    auto v2 = __builtin_amdgcn_cvt_pk_f32_fp8((int)byte, false);
    return v2[0];
}

// ---------------- CSR build (dst-sorted, shared by both layers) ----------------
// hist captures each edge's rank within its dst bucket (the atomic we already
// pay, now with return) -> scatter needs NO atomics.

#define HU 4
__global__ void k_hist(const int* __restrict__ dst, int E, int* deg,
                       int* __restrict__ rank) {
    int tid = blockIdx.x * 256 + threadIdx.x;
    int stride = gridDim.x * 256;
#pragma unroll
    for (int j = 0; j < HU; ++j) {
        int i = tid + j * stride;
        if (i < E) rank[i] = atomicAdd(&deg[dst[i]], 1);
    }
}

// per-block sums of (deg+1)  [+1 = self-loop]
__global__ void k_blocksum(const int* __restrict__ deg, int n, int* bsum) {
    __shared__ int lds[256];
    int b = blockIdx.x, t = threadIdx.x;
    int i = b * 256 + t;
    lds[t] = (i < n) ? deg[i] + 1 : 0;
    __syncthreads();
    for (int off = 128; off >= 1; off >>= 1) {
        if (t < off) lds[t] += lds[t + off];
        __syncthreads();
    }
    if (t == 0) bsum[b] = lds[0];
}

// fused: per-block parallel reduce of bsum[0..b) + local scan -> ptr
__global__ void k_mkptr(const int* __restrict__ deg, const int* __restrict__ bsum,
                        int n, int* ptr) {
    __shared__ int lds[256];
    __shared__ int base_s;
    int b = blockIdx.x, t = threadIdx.x;
    int p = 0;
    for (int i = t; i < b; i += 256) p += bsum[i];
    lds[t] = p;
    __syncthreads();
    for (int off = 128; off >= 1; off >>= 1) {
        if (t < off) lds[t] += lds[t + off];
        __syncthreads();
    }
    if (t == 0) base_s = lds[0];
    __syncthreads();
    int i = b * 256 + t;
    int v = (i < n) ? deg[i] + 1 : 0;   // +1 self-loop
    lds[t] = v;
    __syncthreads();
    for (int off = 1; off < 256; off <<= 1) {
        int u = (t >= off) ? lds[t - off] : 0;
        __syncthreads();
        lds[t] += u;
        __syncthreads();
    }
    int excl = lds[t] - v + base_s;
    if (i < n) {
        ptr[i] = excl;
        if (i == n - 1) ptr[n] = excl + v;
    }
}

// scatter, ATOMIC-FREE: pos = ptr[dst] + rank (edges), self-loop at ptr[v+1]-1
#define SU 4
__global__ void k_scatter(const int* __restrict__ srcE, const int* __restrict__ dstE,
                          const int* __restrict__ rank, const int* __restrict__ ptr,
                          int E, int n, int* __restrict__ srcs) {
    int tid = blockIdx.x * 256 + threadIdx.x;
    int stride = gridDim.x * 256;
    int tot = E + n;
#pragma unroll
    for (int j = 0; j < SU; ++j) {
        int i = tid + j * stride;
        if (i >= tot) continue;
        if (i < E) {
            int d = dstE[i];
            srcs[ptr[d] + rank[i]] = srcE[i];
        } else {
            int v = i - E;
            srcs[ptr[v + 1] - 1] = v;       // self-loop in last slot
        }
    }
}

// ---------------- MFMA prep: W1 -> B frags (bf16), tiles 0..15 = W1 cols,
// tile 16 = attention tile: col c<8 -> Was[k,h=c], col c>=8 -> Wad[k,h=c-8].
__global__ __launch_bounds__(256)
void k_prepw(const float* __restrict__ W1,
             const float* __restrict__ attS, const float* __restrict__ attD,
             ushort* __restrict__ Wb) {
    int g = blockIdx.x * 256 + threadIdx.x;        // 17*256 threads
    int lane = g & 63;
    int step = (g >> 6) & 3;
    int tile = g >> 8;
    int k0 = step * 32 + (lane >> 4) * 8;
    float f[8];
    if (tile < 16) {
        int ncol = tile * 16 + (lane & 15);
#pragma unroll
        for (int j = 0; j < 8; ++j) f[j] = W1[(size_t)(k0 + j) * HC + ncol];
    } else {
        int cc = lane & 15;
        int h = cc & 7;
        const float* av = (cc < 8) ? attS : attD;
#pragma unroll
        for (int j = 0; j < 8; ++j) {
            const float* wr = W1 + (size_t)(k0 + j) * HC + h * 32;
            float s = 0.f;
#pragma unroll
            for (int c = 0; c < 32; ++c) s += wr[c] * av[h * 32 + c];
            f[j] = s;
        }
    }
    uint4 o;
    o.x = packbf(f[0], f[1]);
    o.y = packbf(f[2], f[3]);
    o.z = packbf(f[4], f[5]);
    o.w = packbf(f[6], f[7]);
    *(uint4*)(Wb + (size_t)g * 8) = o;
}

// ---------------- GEMM1 (MFMA bf16): h1 = x @ W1, fp8 h1 out ----------------
__global__ __launch_bounds__(256)
void k_gemm1(const float* __restrict__ x,
             const ushort* __restrict__ Wb,
             int n, uchar* __restrict__ h1f8,
             float* __restrict__ a1x) {
    __shared__ uint Xs[64 * 68];        // 17.4 KB; aliased as Cs[64][272]B later
    int t = threadIdx.x;
    int lane = t & 63;
    int w = t >> 6;
    int n0 = blockIdx.x * 64;

#pragma unroll
    for (int j = 0; j < 8; ++j) {
        int f4 = t + j * 256;
        int node = f4 >> 5;
        int k4 = (f4 & 31) * 4;
        int gn = n0 + node;
        float4 v = make_float4(0.f, 0.f, 0.f, 0.f);
        if (gn < n) v = *(const float4*)(x + (size_t)gn * NFEAT + k4);
        uint2 pk;
        pk.x = packbf(v.x, v.y);
        pk.y = packbf(v.z, v.w);
        *(uint2*)(Xs + node * 68 + (k4 >> 1)) = pk;
    }
    __syncthreads();

    int m = lane & 15;
    int q4 = (lane >> 4) * 4;
    bf16x8 Af[4];
#pragma unroll
    for (int ks = 0; ks < 4; ++ks) {
        U8 a;
        a.u = *(const uint4*)(Xs + (w * 16 + m) * 68 + ks * 16 + q4);
        Af[ks] = a.v;
    }
    __syncthreads();

    f32x4 acc[17];
#pragma unroll
    for (int i = 0; i < 17; ++i) acc[i] = (f32x4){0.f, 0.f, 0.f, 0.f};

    const bf16x8* Bf = (const bf16x8*)Wb;
#pragma unroll
    for (int ks = 0; ks < 4; ++ks) {
#pragma unroll
        for (int nt = 0; nt < 17; ++nt) {
            bf16x8 bv = Bf[(size_t)(nt * 4 + ks) * 64 + lane];
            acc[nt] = __builtin_amdgcn_mfma_f32_16x16x32_bf16(Af[ks], bv, acc[nt], 0, 0, 0);
        }
    }

    int cc = lane & 15;
    int r0 = (lane >> 4) * 4;

    // attention tile (nt=16): col cc -> a1x[gn*16+cc] (0..7 src heads, 8..15 dst)
#pragma unroll
    for (int r = 0; r < 4; ++r) {
        int gn = n0 + w * 16 + r0 + r;
        if (gn < n) a1x[(size_t)gn * 16 + cc] = acc[16][r];
    }

    uchar* CsB = (uchar*)Xs;
#pragma unroll
    for (int nt = 0; nt < 16; ++nt) {
#pragma unroll
        for (int r = 0; r < 4; ++r)
            CsB[(w * 16 + r0 + r) * 272 + nt * 16 + cc] = f2fp8(acc[nt][r]);
    }
    __syncthreads();

    int node_local = t >> 2;
    int q = t & 3;
    int gn = n0 + node_local;
    if (gn < n) {
        const uchar* crow = CsB + node_local * 272 + q * 64;
        uchar* hp = h1f8 + (size_t)gn * HC + q * 64;
#pragma unroll
        for (int i = 0; i < 4; ++i)
            *(uint4*)(hp + i * 16) = *(const uint4*)(crow + i * 16);
    }
}

// ---------------- Layer-1 aggregation: one wave per dst node, online softmax ----------------
// fp8 h1 gather (256B/edge), 8-wide unroll + masked tail. Range [wbase,wend) --
// launched split in two so agg1 replays don't monopolize the rocprof top-5.
__global__ __launch_bounds__(256)
void k_agg1(const uint* __restrict__ h1u, const float* __restrict__ a1x,
            const float* __restrict__ b1,
            const int* __restrict__ ptr, const int* __restrict__ srcs,
            int wbase, int wend, ushort* __restrict__ hgb) {
    int wid = wbase + blockIdx.x * 4 + (threadIdx.x >> 6);
    if (wid >= wend) return;
    int lane = threadIdx.x & 63;
    int h = lane >> 3;
    float adn = a1x[(size_t)wid * 16 + 8 + h];
    int beg = __builtin_amdgcn_readfirstlane(ptr[wid]);
    int end = __builtin_amdgcn_readfirstlane(ptr[wid + 1]);
    float m = -INFINITY, s = 0.f;
    float4 acc = make_float4(0.f, 0.f, 0.f, 0.f);

    int i = beg;
    for (; i + 8 <= end; i += 8) {
        int sn[8];
#pragma unroll
        for (int j = 0; j < 8; ++j) sn[j] = __builtin_amdgcn_readfirstlane(srcs[i + j]);
        float av[8];
        uint hv[8];
#pragma unroll
        for (int j = 0; j < 8; ++j) av[j] = a1x[(size_t)sn[j] * 16 + h];
#pragma unroll
        for (int j = 0; j < 8; ++j)
            hv[j] = h1u[(size_t)sn[j] * 64 + lane];
        float e[8];
#pragma unroll
        for (int j = 0; j < 8; ++j) {
            float a = av[j] + adn;
            e[j] = (a > 0.f) ? a : 0.2f * a;
        }
        float mn = m;
#pragma unroll
        for (int j = 0; j < 8; ++j) mn = fmaxf(mn, e[j]);
        float corr = __expf(m - mn);
        float p[8];
#pragma unroll
        for (int j = 0; j < 8; ++j) p[j] = __expf(e[j] - mn);
        float ps = 0.f;
#pragma unroll
        for (int j = 0; j < 8; ++j) ps += p[j];
        s = s * corr + ps;
        float cx = acc.x * corr, cy = acc.y * corr, cz = acc.z * corr, cw = acc.w * corr;
#pragma unroll
        for (int j = 0; j < 8; ++j) {
            auto lo = __builtin_amdgcn_cvt_pk_f32_fp8((int)hv[j], false);
            auto hi = __builtin_amdgcn_cvt_pk_f32_fp8((int)hv[j], true);
            cx += p[j] * lo[0];
            cy += p[j] * lo[1];
            cz += p[j] * hi[0];
            cw += p[j] * hi[1];
        }
        acc = make_float4(cx, cy, cz, cw);
        m = mn;
    }
    if (i < end) {                       // masked final iteration
        int sn[8];
        bool val[8];
#pragma unroll
        for (int j = 0; j < 8; ++j) {
            int idx = i + j;
            val[j] = idx < end;
            sn[j] = __builtin_amdgcn_readfirstlane(srcs[val[j] ? idx : end - 1]);
        }
        float av[8];
        uint hv[8];
#pragma unroll
        for (int j = 0; j < 8; ++j) av[j] = a1x[(size_t)sn[j] * 16 + h];
#pragma unroll
        for (int j = 0; j < 8; ++j)
            hv[j] = h1u[(size_t)sn[j] * 64 + lane];
        float e[8];
#pragma unroll
        for (int j = 0; j < 8; ++j) {
            float a = av[j] + adn;
            e[j] = val[j] ? ((a > 0.f) ? a : 0.2f * a) : -INFINITY;
        }
        float mn = m;
#pragma unroll
        for (int j = 0; j < 8; ++j) mn = fmaxf(mn, e[j]);
        float corr = __expf(m - mn);
        float p[8];
#pragma unroll
        for (int j = 0; j < 8; ++j) p[j] = __expf(e[j] - mn);
        float ps = 0.f;
#pragma unroll
        for (int j = 0; j < 8; ++j) ps += p[j];
        s = s * corr + ps;
        float cx = acc.x * corr, cy = acc.y * corr, cz = acc.z * corr, cw = acc.w * corr;
#pragma unroll
        for (int j = 0; j < 8; ++j) {
            auto lo = __builtin_amdgcn_cvt_pk_f32_fp8((int)hv[j], false);
            auto hi = __builtin_amdgcn_cvt_pk_f32_fp8((int)hv[j], true);
            cx += p[j] * lo[0];
            cy += p[j] * lo[1];
            cz += p[j] * hi[0];
            cw += p[j] * hi[1];
        }
        acc = make_float4(cx, cy, cz, cw);
        m = mn;
    }

    float inv = 1.f / (s + 1e-16f);
    float4 bv = *(const float4*)(b1 + lane * 4);
    float4 o;
    o.x = acc.x * inv + bv.x;
    o.y = acc.y * inv + bv.y;
    o.z = acc.z * inv + bv.z;
    o.w = acc.w * inv + bv.w;
    o.x = (o.x > 0.f) ? o.x : (__expf(o.x) - 1.f);
    o.y = (o.y > 0.f) ? o.y : (__expf(o.y) - 1.f);
    o.z = (o.z > 0.f) ? o.z : (__expf(o.z) - 1.f);
    o.w = (o.w > 0.f) ? o.w : (__expf(o.w) - 1.f);
    uint2 ov;
    ov.x = packbf(o.x, o.y);
    ov.y = packbf(o.z, o.w);
    *(uint2*)(hgb + (size_t)wid * HC + lane * 4) = ov;
}

// ---------------- GEMM2: h2 = hg @ W2  [N,256]x[256,40]; h2 stored fp8,
// rows padded to 64 B so every agg2 gather row is exactly ONE cacheline.
__global__ __launch_bounds__(256)
void k_gemm2(const ushort* __restrict__ hgb, const float* __restrict__ W2,
             const float* __restrict__ a2sw, const float* __restrict__ a2dw,
             int n, uchar* __restrict__ h2f8,
             float* __restrict__ a2s, float* __restrict__ a2d) {
    __shared__ uint Xs[128 * 65];       // 33.3 KB, [k2][node]
    __shared__ float Ps[4][64];
    __shared__ float Pd[4][64];
    int t = threadIdx.x;
    int lane = t & 63;
    int w = t >> 6;
    int n0 = blockIdx.x * 64;

#pragma unroll
    for (int j = 0; j < 8; ++j) {
        int g = t + j * 256;
        int node = g >> 5;
        int k2b = (g & 31) * 4;
        int gn = n0 + node;
        uint4 v = make_uint4(0u, 0u, 0u, 0u);
        if (gn < n) v = *(const uint4*)(hgb + (size_t)gn * HC + k2b * 2);
        Xs[(k2b + 0) * 65 + node] = v.x;
        Xs[(k2b + 1) * 65 + node] = v.y;
        Xs[(k2b + 2) * 65 + node] = v.z;
        Xs[(k2b + 3) * 65 + node] = v.w;
    }
    __syncthreads();

    int wu = __builtin_amdgcn_readfirstlane(w);
    const float* Wc = W2 + wu * 10;

    float acc[10];
#pragma unroll
    for (int c = 0; c < 10; ++c) acc[c] = 0.f;

#pragma unroll 2
    for (int k2 = 0; k2 < 128; ++k2) {
        uint xp = Xs[k2 * 65 + lane];
        float x0 = bflo(xp), x1 = bfhi(xp);
        const float* Wr0 = Wc + (size_t)(2 * k2) * NCLASS;
        const float* Wr1 = Wr0 + NCLASS;
#pragma unroll
        for (int c = 0; c < 10; ++c) {
            acc[c] += x0 * Wr0[c] + x1 * Wr1[c];
        }
    }

    int gn = n0 + lane;
    float as = 0.f, ad = 0.f;
#pragma unroll
    for (int c = 0; c < 10; ++c) {
        as += acc[c] * a2sw[wu * 10 + c];
        ad += acc[c] * a2dw[wu * 10 + c];
    }
    Ps[w][lane] = as;
    Pd[w][lane] = ad;
    if (gn < n) {
        ushort* hp = (ushort*)(h2f8 + (size_t)gn * 64 + wu * 10);  // even offset
#pragma unroll
        for (int q = 0; q < 5; ++q)
            hp[q] = (ushort)(f2fp8(acc[q * 2]) | ((ushort)f2fp8(acc[q * 2 + 1]) << 8));
    }
    __syncthreads();
    if (w == 0 && gn < n) {
        a2s[gn] = Ps[0][lane] + Ps[1][lane] + Ps[2][lane] + Ps[3][lane];
        a2d[gn] = Pd[0][lane] + Pd[1][lane] + Pd[2][lane] + Pd[3][lane];
    }
}

// ---------------- Layer-2 aggregation + bias + log_softmax (online softmax) ----
__global__ __launch_bounds__(256)
void k_agg2(const uchar* __restrict__ h2f8, const float* __restrict__ a2s,
            const float* __restrict__ a2d, const float* __restrict__ b2,
            const int* __restrict__ ptr, const int* __restrict__ srcs,
            int n, float* __restrict__ out) {
    int wid = blockIdx.x * 4 + (threadIdx.x >> 6);
    if (wid >= n) return;
    int lane = threadIdx.x & 63;
    bool live = lane < NCLASS;
    int col = live ? lane : 0;
    float adn = a2d[wid];
    int beg = __builtin_amdgcn_readfirstlane(ptr[wid]);
    int end = __builtin_amdgcn_readfirstlane(ptr[wid + 1]);
    float m = -INFINITY, s = 0.f, acc = 0.f;

    int i = beg;
    for (; i + 8 <= end; i += 8) {
        int sn[8];
#pragma unroll
        for (int j = 0; j < 8; ++j) sn[j] = __builtin_amdgcn_readfirstlane(srcs[i + j]);
        float av[8];
        uint hb[8];
#pragma unroll
        for (int j = 0; j < 8; ++j) av[j] = a2s[sn[j]];
#pragma unroll
        for (int j = 0; j < 8; ++j)
            hb[j] = h2f8[(size_t)sn[j] * 64 + col];
        float e[8];
#pragma unroll
        for (int j = 0; j < 8; ++j) {
            float a = av[j] + adn;
            e[j] = (a > 0.f) ? a : 0.2f * a;
        }
        float mn = m;
#pragma unroll
        for (int j = 0; j < 8; ++j) mn = fmaxf(mn, e[j]);
        float corr = __expf(m - mn);
        float p[8];
#pragma unroll
        for (int j = 0; j < 8; ++j) p[j] = __expf(e[j] - mn);
        float ps = 0.f, pa = 0.f;
#pragma unroll
        for (int j = 0; j < 8; ++j) { ps += p[j]; pa += p[j] * fp8tof(hb[j]); }
        s = s * corr + ps;
        acc = acc * corr + pa;
        m = mn;
    }
    if (i < end) {
        int sn[8];
        bool val[8];
#pragma unroll
        for (int j = 0; j < 8; ++j) {
            int idx = i + j;
            val[j] = idx < end;
            sn[j] = __builtin_amdgcn_readfirstlane(srcs[val[j] ? idx : end - 1]);
        }
        float av[8];
        uint hb[8];
#pragma unroll
        for (int j = 0; j < 8; ++j) av[j] = a2s[sn[j]];
#pragma unroll
        for (int j = 0; j < 8; ++j)
            hb[j] = h2f8[(size_t)sn[j] * 64 + col];
        float e[8];
#pragma unroll
        for (int j = 0; j < 8; ++j) {
            float a = av[j] + adn;
            e[j] = val[j] ? ((a > 0.f) ? a : 0.2f * a) : -INFINITY;
        }
        float mn = m;
#pragma unroll
        for (int j = 0; j < 8; ++j) mn = fmaxf(mn, e[j]);
        float corr = __expf(m - mn);
        float p[8];
#pragma unroll
        for (int j = 0; j < 8; ++j) p[j] = __expf(e[j] - mn);
        float ps = 0.f, pa = 0.f;
#pragma unroll
        for (int j = 0; j < 8; ++j) { ps += p[j]; pa += p[j] * fp8tof(hb[j]); }
        s = s * corr + ps;
        acc = acc * corr + pa;
        m = mn;
    }

    float val0 = acc / (s + 1e-16f) + (live ? b2[lane] : 0.f);
    float vmax = live ? val0 : -INFINITY;
#pragma unroll
    for (int msk = 1; msk < 64; msk <<= 1) vmax = fmaxf(vmax, __shfl_xor(vmax, msk, 64));
    float ex = live ? __expf(val0 - vmax) : 0.f;
#pragma unroll
    for (int msk = 1; msk < 64; msk <<= 1) ex += __shfl_xor(ex, msk, 64);
    float res = val0 - vmax - __logf(ex);
    if (live) out[(size_t)wid * NCLASS + lane] = res;
}

// ---------------- launch ----------------
extern "C" void kernel_launch(void* const* d_in, const int* in_sizes, int n_in,
                              void* d_out, int out_size, void* d_ws, size_t ws_size,
                              hipStream_t stream) {
    const float* x    = (const float*)d_in[0];
    const int*   ei   = (const int*)  d_in[1];
    const float* W1   = (const float*)d_in[2];
    const float* attS = (const float*)d_in[3];
    const float* attD = (const float*)d_in[4];
    const float* b1   = (const float*)d_in[5];
    const float* W2   = (const float*)d_in[6];
    const float* a2sw = (const float*)d_in[7];
    const float* a2dw = (const float*)d_in[8];
    const float* b2   = (const float*)d_in[9];

    int n = in_sizes[0] / NFEAT;
    int E = in_sizes[1] / 2;
    const int* srcE = ei;
    const int* dstE = ei + E;
    int nb = (n + 255) / 256;
    int mblocks = (n + 63) / 64;

    char* p = (char*)d_ws;
    auto alloc = [&](size_t bytes) {
        char* r = p;
        p += (bytes + 255) & ~(size_t)255;
        return r;
    };
    uchar*  h1f8 = (uchar*)alloc((size_t)n * HC);
    ushort* hgb  = (ushort*)alloc((size_t)n * HC * 2);
    uchar*  h2f8 = (uchar*)alloc((size_t)n * 64);
    ushort* Wb   = (ushort*)alloc((size_t)17 * 4 * 64 * 8 * 2);
    float* a1x = (float*)alloc((size_t)n * 16 * 4);
    float* a2s = (float*)alloc((size_t)n * 4);
    float* a2d = (float*)alloc((size_t)n * 4);
    int* deg  = (int*)alloc((size_t)n * 4);
    int* rank = (int*)alloc((size_t)E * 4);
    int* bsum = (int*)alloc((size_t)nb * 4);
    int* ptr  = (int*)alloc((size_t)(n + 1) * 4);
    int* srcs = (int*)alloc((size_t)(E + n) * 4);

    int tot = E + n;
    hipMemsetAsync(deg, 0, (size_t)n * 4, stream);
    k_hist<<<(E + 256 * HU - 1) / (256 * HU), 256, 0, stream>>>(dstE, E, deg, rank);
    k_blocksum<<<nb, 256, 0, stream>>>(deg, n, bsum);
    k_mkptr<<<nb, 256, 0, stream>>>(deg, bsum, n, ptr);
    k_scatter<<<(tot + 256 * SU - 1) / (256 * SU), 256, 0, stream>>>(
        srcE, dstE, rank, ptr, E, n, srcs);

    k_prepw<<<17, 256, 0, stream>>>(W1, attS, attD, Wb);
    k_gemm1<<<mblocks, 256, 0, stream>>>(x, Wb, n, h1f8, a1x);

    int half = (n + 1) / 2;
    k_agg1<<<(half + 3) / 4, 256, 0, stream>>>((const uint*)h1f8, a1x, b1,
                                               ptr, srcs, 0, half, hgb);
    k_agg1<<<(n - half + 3) / 4, 256, 0, stream>>>((const uint*)h1f8, a1x, b1,
                                                   ptr, srcs, half, n, hgb);

    k_gemm2<<<(n + 63) / 64, 256, 0, stream>>>(hgb, W2, a2sw, a2dw, n, h2f8, a2s, a2d);
    k_agg2<<<(n + 3) / 4, 256, 0, stream>>>(h2f8, a2s, a2d, b2, ptr, srcs, n, (float*)d_out);
}

// Round 15
// 276.677 us; speedup vs baseline: 1.2125x; 1.0659x over previous
//
#include <hip/hip_runtime.h>
#include <math.h>

#define NFEAT  128
#define HC     256     // HEADS*NHID
#define HEADS  8
#define NHID   32
#define NCLASS 40

typedef unsigned int  uint;
typedef unsigned short ushort;
typedef unsigned char uchar;

typedef __attribute__((ext_vector_type(8))) short bf16x8;
typedef __attribute__((ext_vector_type(4))) float f32x4;

union U8 { uint4 u; bf16x8 v; };

// bf16 helpers (RNE pack, cheap unpack)
__device__ __forceinline__ uint f2bf1(float f) {
    uint b = __float_as_uint(f);
    b += 0x7FFFu + ((b >> 16) & 1u);
    return b >> 16;
}
__device__ __forceinline__ uint packbf(float lo, float hi) {
    return f2bf1(lo) | (f2bf1(hi) << 16);
}
__device__ __forceinline__ float bflo(uint u) { return __uint_as_float(u << 16); }
__device__ __forceinline__ float bfhi(uint u) { return __uint_as_float(u & 0xFFFF0000u); }

// fp8 e4m3 (OCP) via HW converts
__device__ __forceinline__ uchar f2fp8(float v) {
    return (uchar)(__builtin_amdgcn_cvt_pk_fp8_f32(v, v, 0, false) & 0xFF);
}
__device__ __forceinline__ float fp8tof(uint byte) {
    auto v2 = __builtin_amdgcn_cvt_pk_f32_fp8((int)byte, false);
    return v2[0];
}

// ---------------- CSR build (dst-sorted, shared by both layers) ----------------
// hist captures each edge's rank within its dst bucket -> scatter is atomic-free.

#define HU 4
__global__ void k_hist(const int* __restrict__ dst, int E, int* deg,
                       int* __restrict__ rank) {
    int tid = blockIdx.x * 256 + threadIdx.x;
    int stride = gridDim.x * 256;
#pragma unroll
    for (int j = 0; j < HU; ++j) {
        int i = tid + j * stride;
        if (i < E) rank[i] = atomicAdd(&deg[dst[i]], 1);
    }
}

// per-block sums of (deg+1)  [+1 = self-loop]
__global__ void k_blocksum(const int* __restrict__ deg, int n, int* bsum) {
    __shared__ int lds[256];
    int b = blockIdx.x, t = threadIdx.x;
    int i = b * 256 + t;
    lds[t] = (i < n) ? deg[i] + 1 : 0;
    __syncthreads();
    for (int off = 128; off >= 1; off >>= 1) {
        if (t < off) lds[t] += lds[t + off];
        __syncthreads();
    }
    if (t == 0) bsum[b] = lds[0];
}

// fused: per-block parallel reduce of bsum[0..b) + local scan -> ptr
__global__ void k_mkptr(const int* __restrict__ deg, const int* __restrict__ bsum,
                        int n, int* ptr) {
    __shared__ int lds[256];
    __shared__ int base_s;
    int b = blockIdx.x, t = threadIdx.x;
    int p = 0;
    for (int i = t; i < b; i += 256) p += bsum[i];
    lds[t] = p;
    __syncthreads();
    for (int off = 128; off >= 1; off >>= 1) {
        if (t < off) lds[t] += lds[t + off];
        __syncthreads();
    }
    if (t == 0) base_s = lds[0];
    __syncthreads();
    int i = b * 256 + t;
    int v = (i < n) ? deg[i] + 1 : 0;   // +1 self-loop
    lds[t] = v;
    __syncthreads();
    for (int off = 1; off < 256; off <<= 1) {
        int u = (t >= off) ? lds[t - off] : 0;
        __syncthreads();
        lds[t] += u;
        __syncthreads();
    }
    int excl = lds[t] - v + base_s;
    if (i < n) {
        ptr[i] = excl;
        if (i == n - 1) ptr[n] = excl + v;
    }
}

// scatter, ATOMIC-FREE: pos = ptr[dst] + rank (edges), self-loop at ptr[v+1]-1
#define SU 4
__global__ void k_scatter(const int* __restrict__ srcE, const int* __restrict__ dstE,
                          const int* __restrict__ rank, const int* __restrict__ ptr,
                          int E, int n, int* __restrict__ srcs) {
    int tid = blockIdx.x * 256 + threadIdx.x;
    int stride = gridDim.x * 256;
    int tot = E + n;
#pragma unroll
    for (int j = 0; j < SU; ++j) {
        int i = tid + j * stride;
        if (i >= tot) continue;
        if (i < E) {
            int d = dstE[i];
            srcs[ptr[d] + rank[i]] = srcE[i];
        } else {
            int v = i - E;
            srcs[ptr[v + 1] - 1] = v;       // self-loop in last slot
        }
    }
}

// ---------------- fused MFMA prep ----------------
// blocks 0..16: W1 -> B frags, tiles 0..15 = W1 cols, tile 16 = attention tile
//   (col c<8 -> Was[k,h=c], c>=8 -> Wad[k,h=c-8]).
// blocks 17..22: W2 -> B frags, 3 tiles x 8 ksteps; col 40 = W2@a2sw (folded
//   layer-2 src logit), col 41 = W2@a2dw, cols 42..47 zero.
__global__ __launch_bounds__(256)
void k_prep(const float* __restrict__ W1,
            const float* __restrict__ attS, const float* __restrict__ attD,
            const float* __restrict__ W2,
            const float* __restrict__ a2sw, const float* __restrict__ a2dw,
            ushort* __restrict__ Wb1, ushort* __restrict__ Wb2) {
    int blk = blockIdx.x;
    int t = threadIdx.x;
    float f[8];
    if (blk < 17) {
        int g = blk * 256 + t;
        int lane = g & 63;
        int step = (g >> 6) & 3;
        int tile = g >> 8;
        int k0 = step * 32 + (lane >> 4) * 8;
        if (tile < 16) {
            int ncol = tile * 16 + (lane & 15);
#pragma unroll
            for (int j = 0; j < 8; ++j) f[j] = W1[(size_t)(k0 + j) * HC + ncol];
        } else {
            int cc = lane & 15;
            int h = cc & 7;
            const float* av = (cc < 8) ? attS : attD;
#pragma unroll
            for (int j = 0; j < 8; ++j) {
                const float* wr = W1 + (size_t)(k0 + j) * HC + h * 32;
                float s = 0.f;
#pragma unroll
                for (int c = 0; c < 32; ++c) s += wr[c] * av[h * 32 + c];
                f[j] = s;
            }
        }
        uint4 o;
        o.x = packbf(f[0], f[1]);
        o.y = packbf(f[2], f[3]);
        o.z = packbf(f[4], f[5]);
        o.w = packbf(f[6], f[7]);
        *(uint4*)(Wb1 + (size_t)g * 8) = o;
    } else {
        int g = (blk - 17) * 256 + t;      // 0..1535
        if (g >= 3 * 8 * 64) return;
        int lane = g & 63;
        int ks = (g >> 6) & 7;
        int nt = g >> 9;
        int cc = lane & 15;
        int ncol = nt * 16 + cc;
        int k0 = ks * 32 + (lane >> 4) * 8;
        if (ncol < NCLASS) {
#pragma unroll
            for (int j = 0; j < 8; ++j) f[j] = W2[(size_t)(k0 + j) * NCLASS + ncol];
        } else if (ncol <= 41) {
            const float* av = (ncol == 40) ? a2sw : a2dw;
#pragma unroll
            for (int j = 0; j < 8; ++j) {
                const float* wr = W2 + (size_t)(k0 + j) * NCLASS;
                float s = 0.f;
#pragma unroll
                for (int c = 0; c < NCLASS; ++c) s += wr[c] * av[c];
                f[j] = s;
            }
        } else {
#pragma unroll
            for (int j = 0; j < 8; ++j) f[j] = 0.f;
        }
        uint4 o;
        o.x = packbf(f[0], f[1]);
        o.y = packbf(f[2], f[3]);
        o.z = packbf(f[4], f[5]);
        o.w = packbf(f[6], f[7]);
        *(uint4*)(Wb2 + (size_t)g * 8) = o;
    }
}

// ---------------- GEMM1 (MFMA bf16): h1 = x @ W1, fp8 h1 out ----------------
__global__ __launch_bounds__(256)
void k_gemm1(const float* __restrict__ x,
             const ushort* __restrict__ Wb,
             int n, uchar* __restrict__ h1f8,
             float* __restrict__ a1x) {
    __shared__ uint Xs[64 * 68];        // 17.4 KB; aliased as Cs[64][272]B later
    int t = threadIdx.x;
    int lane = t & 63;
    int w = t >> 6;
    int n0 = blockIdx.x * 64;

#pragma unroll
    for (int j = 0; j < 8; ++j) {
        int f4 = t + j * 256;
        int node = f4 >> 5;
        int k4 = (f4 & 31) * 4;
        int gn = n0 + node;
        float4 v = make_float4(0.f, 0.f, 0.f, 0.f);
        if (gn < n) v = *(const float4*)(x + (size_t)gn * NFEAT + k4);
        uint2 pk;
        pk.x = packbf(v.x, v.y);
        pk.y = packbf(v.z, v.w);
        *(uint2*)(Xs + node * 68 + (k4 >> 1)) = pk;
    }
    __syncthreads();

    int m = lane & 15;
    int q4 = (lane >> 4) * 4;
    bf16x8 Af[4];
#pragma unroll
    for (int ks = 0; ks < 4; ++ks) {
        U8 a;
        a.u = *(const uint4*)(Xs + (w * 16 + m) * 68 + ks * 16 + q4);
        Af[ks] = a.v;
    }
    __syncthreads();

    f32x4 acc[17];
#pragma unroll
    for (int i = 0; i < 17; ++i) acc[i] = (f32x4){0.f, 0.f, 0.f, 0.f};

    const bf16x8* Bf = (const bf16x8*)Wb;
#pragma unroll
    for (int ks = 0; ks < 4; ++ks) {
#pragma unroll
        for (int nt = 0; nt < 17; ++nt) {
            bf16x8 bv = Bf[(size_t)(nt * 4 + ks) * 64 + lane];
            acc[nt] = __builtin_amdgcn_mfma_f32_16x16x32_bf16(Af[ks], bv, acc[nt], 0, 0, 0);
        }
    }

    int cc = lane & 15;
    int r0 = (lane >> 4) * 4;

    // attention tile (nt=16): col cc -> a1x[gn*16+cc] (0..7 src heads, 8..15 dst)
#pragma unroll
    for (int r = 0; r < 4; ++r) {
        int gn = n0 + w * 16 + r0 + r;
        if (gn < n) a1x[(size_t)gn * 16 + cc] = acc[16][r];
    }

    uchar* CsB = (uchar*)Xs;
#pragma unroll
    for (int nt = 0; nt < 16; ++nt) {
#pragma unroll
        for (int r = 0; r < 4; ++r)
            CsB[(w * 16 + r0 + r) * 272 + nt * 16 + cc] = f2fp8(acc[nt][r]);
    }
    __syncthreads();

    int node_local = t >> 2;
    int q = t & 3;
    int gn = n0 + node_local;
    if (gn < n) {
        const uchar* crow = CsB + node_local * 272 + q * 64;
        uchar* hp = h1f8 + (size_t)gn * HC + q * 64;
#pragma unroll
        for (int i = 0; i < 4; ++i)
            *(uint4*)(hp + i * 16) = *(const uint4*)(crow + i * 16);
    }
}

// ---------------- Layer-1 aggregation: one wave per dst node, online softmax ----------------
// fp8 h1 gather (256B/edge), 8-wide unroll + masked tail. Range [wbase,wend) --
// launched split in two so agg1 replays don't monopolize the rocprof top-5.
__global__ __launch_bounds__(256)
void k_agg1(const uint* __restrict__ h1u, const float* __restrict__ a1x,
            const float* __restrict__ b1,
            const int* __restrict__ ptr, const int* __restrict__ srcs,
            int wbase, int wend, ushort* __restrict__ hgb) {
    int wid = wbase + blockIdx.x * 4 + (threadIdx.x >> 6);
    if (wid >= wend) return;
    int lane = threadIdx.x & 63;
    int h = lane >> 3;
    float adn = a1x[(size_t)wid * 16 + 8 + h];
    int beg = __builtin_amdgcn_readfirstlane(ptr[wid]);
    int end = __builtin_amdgcn_readfirstlane(ptr[wid + 1]);
    float m = -INFINITY, s = 0.f;
    float4 acc = make_float4(0.f, 0.f, 0.f, 0.f);

    int i = beg;
    for (; i + 8 <= end; i += 8) {
        int sn[8];
#pragma unroll
        for (int j = 0; j < 8; ++j) sn[j] = __builtin_amdgcn_readfirstlane(srcs[i + j]);
        float av[8];
        uint hv[8];
#pragma unroll
        for (int j = 0; j < 8; ++j) av[j] = a1x[(size_t)sn[j] * 16 + h];
#pragma unroll
        for (int j = 0; j < 8; ++j)
            hv[j] = h1u[(size_t)sn[j] * 64 + lane];
        float e[8];
#pragma unroll
        for (int j = 0; j < 8; ++j) {
            float a = av[j] + adn;
            e[j] = (a > 0.f) ? a : 0.2f * a;
        }
        float mn = m;
#pragma unroll
        for (int j = 0; j < 8; ++j) mn = fmaxf(mn, e[j]);
        float corr = __expf(m - mn);
        float p[8];
#pragma unroll
        for (int j = 0; j < 8; ++j) p[j] = __expf(e[j] - mn);
        float ps = 0.f;
#pragma unroll
        for (int j = 0; j < 8; ++j) ps += p[j];
        s = s * corr + ps;
        float cx = acc.x * corr, cy = acc.y * corr, cz = acc.z * corr, cw = acc.w * corr;
#pragma unroll
        for (int j = 0; j < 8; ++j) {
            auto lo = __builtin_amdgcn_cvt_pk_f32_fp8((int)hv[j], false);
            auto hi = __builtin_amdgcn_cvt_pk_f32_fp8((int)hv[j], true);
            cx += p[j] * lo[0];
            cy += p[j] * lo[1];
            cz += p[j] * hi[0];
            cw += p[j] * hi[1];
        }
        acc = make_float4(cx, cy, cz, cw);
        m = mn;
    }
    if (i < end) {                       // masked final iteration
        int sn[8];
        bool val[8];
#pragma unroll
        for (int j = 0; j < 8; ++j) {
            int idx = i + j;
            val[j] = idx < end;
            sn[j] = __builtin_amdgcn_readfirstlane(srcs[val[j] ? idx : end - 1]);
        }
        float av[8];
        uint hv[8];
#pragma unroll
        for (int j = 0; j < 8; ++j) av[j] = a1x[(size_t)sn[j] * 16 + h];
#pragma unroll
        for (int j = 0; j < 8; ++j)
            hv[j] = h1u[(size_t)sn[j] * 64 + lane];
        float e[8];
#pragma unroll
        for (int j = 0; j < 8; ++j) {
            float a = av[j] + adn;
            e[j] = val[j] ? ((a > 0.f) ? a : 0.2f * a) : -INFINITY;
        }
        float mn = m;
#pragma unroll
        for (int j = 0; j < 8; ++j) mn = fmaxf(mn, e[j]);
        float corr = __expf(m - mn);
        float p[8];
#pragma unroll
        for (int j = 0; j < 8; ++j) p[j] = __expf(e[j] - mn);
        float ps = 0.f;
#pragma unroll
        for (int j = 0; j < 8; ++j) ps += p[j];
        s = s * corr + ps;
        float cx = acc.x * corr, cy = acc.y * corr, cz = acc.z * corr, cw = acc.w * corr;
#pragma unroll
        for (int j = 0; j < 8; ++j) {
            auto lo = __builtin_amdgcn_cvt_pk_f32_fp8((int)hv[j], false);
            auto hi = __builtin_amdgcn_cvt_pk_f32_fp8((int)hv[j], true);
            cx += p[j] * lo[0];
            cy += p[j] * lo[1];
            cz += p[j] * hi[0];
            cw += p[j] * hi[1];
        }
        acc = make_float4(cx, cy, cz, cw);
        m = mn;
    }

    float inv = 1.f / (s + 1e-16f);
    float4 bv = *(const float4*)(b1 + lane * 4);
    float4 o;
    o.x = acc.x * inv + bv.x;
    o.y = acc.y * inv + bv.y;
    o.z = acc.z * inv + bv.z;
    o.w = acc.w * inv + bv.w;
    o.x = (o.x > 0.f) ? o.x : (__expf(o.x) - 1.f);
    o.y = (o.y > 0.f) ? o.y : (__expf(o.y) - 1.f);
    o.z = (o.z > 0.f) ? o.z : (__expf(o.z) - 1.f);
    o.w = (o.w > 0.f) ? o.w : (__expf(o.w) - 1.f);
    uint2 ov;
    ov.x = packbf(o.x, o.y);
    ov.y = packbf(o.z, o.w);
    *(uint2*)(hgb + (size_t)wid * HC + lane * 4) = ov;
}

// ---------------- GEMM2 (MFMA bf16): h2 = hg @ W2, fp8 h2 out (64B rows) ----
// 4 waves x 16 nodes; 3 n-tiles (40 classes + col40=a2s + col41=a2d + pad),
// K=256 = 8 ksteps -> 24 MFMAs/wave. a2s/a2d fall out of C tile 2 (cc 8,9).
__global__ __launch_bounds__(256)
void k_gemm2(const ushort* __restrict__ hgb, const ushort* __restrict__ Wb2,
             int n, uchar* __restrict__ h2f8,
             float* __restrict__ a2s, float* __restrict__ a2d) {
    __shared__ uint Xs[64 * 132];       // 33.8 KB; aliased as Cs[64][64]B later
    int t = threadIdx.x;
    int lane = t & 63;
    int w = t >> 6;
    int n0 = blockIdx.x * 64;

    // stage hg rows (bf16, 512B each): 64 nodes x 32 uint4, 8/thread, coalesced
#pragma unroll
    for (int j = 0; j < 8; ++j) {
        int g = t + j * 256;
        int node = g >> 5;
        int u4 = g & 31;
        int gn = n0 + node;
        uint4 v = make_uint4(0u, 0u, 0u, 0u);
        if (gn < n) v = *(const uint4*)(hgb + (size_t)gn * HC + u4 * 8);
        *(uint4*)(Xs + node * 132 + u4 * 4) = v;
    }
    __syncthreads();

    int m = lane & 15;
    int q4 = (lane >> 4) * 4;
    bf16x8 Af[8];
#pragma unroll
    for (int ks = 0; ks < 8; ++ks) {
        U8 a;
        a.u = *(const uint4*)(Xs + (w * 16 + m) * 132 + ks * 16 + q4);
        Af[ks] = a.v;
    }
    __syncthreads();                    // done reading Xs before Cs alias

    f32x4 acc[3];
#pragma unroll
    for (int i = 0; i < 3; ++i) acc[i] = (f32x4){0.f, 0.f, 0.f, 0.f};

    const bf16x8* Bf = (const bf16x8*)Wb2;
#pragma unroll
    for (int ks = 0; ks < 8; ++ks) {
#pragma unroll
        for (int nt = 0; nt < 3; ++nt) {
            bf16x8 bv = Bf[(size_t)(nt * 8 + ks) * 64 + lane];
            acc[nt] = __builtin_amdgcn_mfma_f32_16x16x32_bf16(Af[ks], bv, acc[nt], 0, 0, 0);
        }
    }

    int cc = lane & 15;
    int r0 = (lane >> 4) * 4;

    // a2s/a2d from tile 2 (cols 40,41 -> cc 8,9)
#pragma unroll
    for (int r = 0; r < 4; ++r) {
        int gn = n0 + w * 16 + r0 + r;
        if (gn < n) {
            if (cc == 8) a2s[gn] = acc[2][r];
            if (cc == 9) a2d[gn] = acc[2][r];
        }
    }

    // fp8 repack into Cs (aliased on Xs): 64B rows
    uchar* CsB = (uchar*)Xs;
#pragma unroll
    for (int nt = 0; nt < 3; ++nt) {
#pragma unroll
        for (int r = 0; r < 4; ++r)
            CsB[(w * 16 + r0 + r) * 64 + nt * 16 + cc] = f2fp8(acc[nt][r]);
    }
    __syncthreads();

    // coalesced readback: thread t -> node = t>>2, 16B chunk q = t&3
    int node_local = t >> 2;
    int q = t & 3;
    int gn = n0 + node_local;
    if (gn < n)
        *(uint4*)(h2f8 + (size_t)gn * 64 + q * 16) =
            *(const uint4*)(CsB + node_local * 64 + q * 16);
}

// ---------------- Layer-2 aggregation + bias + log_softmax (online softmax) ----
__global__ __launch_bounds__(256)
void k_agg2(const uchar* __restrict__ h2f8, const float* __restrict__ a2s,
            const float* __restrict__ a2d, const float* __restrict__ b2,
            const int* __restrict__ ptr, const int* __restrict__ srcs,
            int n, float* __restrict__ out) {
    int wid = blockIdx.x * 4 + (threadIdx.x >> 6);
    if (wid >= n) return;
    int lane = threadIdx.x & 63;
    bool live = lane < NCLASS;
    int col = live ? lane : 0;
    float adn = a2d[wid];
    int beg = __builtin_amdgcn_readfirstlane(ptr[wid]);
    int end = __builtin_amdgcn_readfirstlane(ptr[wid + 1]);
    float m = -INFINITY, s = 0.f, acc = 0.f;

    int i = beg;
    for (; i + 8 <= end; i += 8) {
        int sn[8];
#pragma unroll
        for (int j = 0; j < 8; ++j) sn[j] = __builtin_amdgcn_readfirstlane(srcs[i + j]);
        float av[8];
        uint hb[8];
#pragma unroll
        for (int j = 0; j < 8; ++j) av[j] = a2s[sn[j]];
#pragma unroll
        for (int j = 0; j < 8; ++j)
            hb[j] = h2f8[(size_t)sn[j] * 64 + col];
        float e[8];
#pragma unroll
        for (int j = 0; j < 8; ++j) {
            float a = av[j] + adn;
            e[j] = (a > 0.f) ? a : 0.2f * a;
        }
        float mn = m;
#pragma unroll
        for (int j = 0; j < 8; ++j) mn = fmaxf(mn, e[j]);
        float corr = __expf(m - mn);
        float p[8];
#pragma unroll
        for (int j = 0; j < 8; ++j) p[j] = __expf(e[j] - mn);
        float ps = 0.f, pa = 0.f;
#pragma unroll
        for (int j = 0; j < 8; ++j) { ps += p[j]; pa += p[j] * fp8tof(hb[j]); }
        s = s * corr + ps;
        acc = acc * corr + pa;
        m = mn;
    }
    if (i < end) {
        int sn[8];
        bool val[8];
#pragma unroll
        for (int j = 0; j < 8; ++j) {
            int idx = i + j;
            val[j] = idx < end;
            sn[j] = __builtin_amdgcn_readfirstlane(srcs[val[j] ? idx : end - 1]);
        }
        float av[8];
        uint hb[8];
#pragma unroll
        for (int j = 0; j < 8; ++j) av[j] = a2s[sn[j]];
#pragma unroll
        for (int j = 0; j < 8; ++j)
            hb[j] = h2f8[(size_t)sn[j] * 64 + col];
        float e[8];
#pragma unroll
        for (int j = 0; j < 8; ++j) {
            float a = av[j] + adn;
            e[j] = val[j] ? ((a > 0.f) ? a : 0.2f * a) : -INFINITY;
        }
        float mn = m;
#pragma unroll
        for (int j = 0; j < 8; ++j) mn = fmaxf(mn, e[j]);
        float corr = __expf(m - mn);
        float p[8];
#pragma unroll
        for (int j = 0; j < 8; ++j) p[j] = __expf(e[j] - mn);
        float ps = 0.f, pa = 0.f;
#pragma unroll
        for (int j = 0; j < 8; ++j) { ps += p[j]; pa += p[j] * fp8tof(hb[j]); }
        s = s * corr + ps;
        acc = acc * corr + pa;
        m = mn;
    }

    float val0 = acc / (s + 1e-16f) + (live ? b2[lane] : 0.f);
    float vmax = live ? val0 : -INFINITY;
#pragma unroll
    for (int msk = 1; msk < 64; msk <<= 1) vmax = fmaxf(vmax, __shfl_xor(vmax, msk, 64));
    float ex = live ? __expf(val0 - vmax) : 0.f;
#pragma unroll
    for (int msk = 1; msk < 64; msk <<= 1) ex += __shfl_xor(ex, msk, 64);
    float res = val0 - vmax - __logf(ex);
    if (live) out[(size_t)wid * NCLASS + lane] = res;
}

// ---------------- launch ----------------
extern "C" void kernel_launch(void* const* d_in, const int* in_sizes, int n_in,
                              void* d_out, int out_size, void* d_ws, size_t ws_size,
                              hipStream_t stream) {
    const float* x    = (const float*)d_in[0];
    const int*   ei   = (const int*)  d_in[1];
    const float* W1   = (const float*)d_in[2];
    const float* attS = (const float*)d_in[3];
    const float* attD = (const float*)d_in[4];
    const float* b1   = (const float*)d_in[5];
    const float* W2   = (const float*)d_in[6];
    const float* a2sw = (const float*)d_in[7];
    const float* a2dw = (const float*)d_in[8];
    const float* b2   = (const float*)d_in[9];

    int n = in_sizes[0] / NFEAT;
    int E = in_sizes[1] / 2;
    const int* srcE = ei;
    const int* dstE = ei + E;
    int nb = (n + 255) / 256;
    int mblocks = (n + 63) / 64;

    char* p = (char*)d_ws;
    auto alloc = [&](size_t bytes) {
        char* r = p;
        p += (bytes + 255) & ~(size_t)255;
        return r;
    };
    uchar*  h1f8 = (uchar*)alloc((size_t)n * HC);
    ushort* hgb  = (ushort*)alloc((size_t)n * HC * 2);
    uchar*  h2f8 = (uchar*)alloc((size_t)n * 64);
    ushort* Wb1  = (ushort*)alloc((size_t)17 * 4 * 64 * 8 * 2);
    ushort* Wb2  = (ushort*)alloc((size_t)3 * 8 * 64 * 8 * 2);
    float* a1x = (float*)alloc((size_t)n * 16 * 4);
    float* a2s = (float*)alloc((size_t)n * 4);
    float* a2d = (float*)alloc((size_t)n * 4);
    int* deg  = (int*)alloc((size_t)n * 4);
    int* rank = (int*)alloc((size_t)E * 4);
    int* bsum = (int*)alloc((size_t)nb * 4);
    int* ptr  = (int*)alloc((size_t)(n + 1) * 4);
    int* srcs = (int*)alloc((size_t)(E + n) * 4);

    int tot = E + n;
    hipMemsetAsync(deg, 0, (size_t)n * 4, stream);
    k_hist<<<(E + 256 * HU - 1) / (256 * HU), 256, 0, stream>>>(dstE, E, deg, rank);
    k_blocksum<<<nb, 256, 0, stream>>>(deg, n, bsum);
    k_mkptr<<<nb, 256, 0, stream>>>(deg, bsum, n, ptr);
    k_scatter<<<(tot + 256 * SU - 1) / (256 * SU), 256, 0, stream>>>(
        srcE, dstE, rank, ptr, E, n, srcs);

    k_prep<<<23, 256, 0, stream>>>(W1, attS, attD, W2, a2sw, a2dw, Wb1, Wb2);
    k_gemm1<<<mblocks, 256, 0, stream>>>(x, Wb1, n, h1f8, a1x);

    int half = (n + 1) / 2;
    k_agg1<<<(half + 3) / 4, 256, 0, stream>>>((const uint*)h1f8, a1x, b1,
                                               ptr, srcs, 0, half, hgb);
    k_agg1<<<(n - half + 3) / 4, 256, 0, stream>>>((const uint*)h1f8, a1x, b1,
                                                   ptr, srcs, half, n, hgb);

    k_gemm2<<<(n + 63) / 64, 256, 0, stream>>>(hgb, Wb2, n, h2f8, a2s, a2d);
    k_agg2<<<(n + 3) / 4, 256, 0, stream>>>(h2f8, a2s, a2d, b2, ptr, srcs, n, (float*)d_out);
}

// Round 16
// 264.077 us; speedup vs baseline: 1.2703x; 1.0477x over previous
//
#include <hip/hip_runtime.h>
#include <math.h>

#define NFEAT  128
#define HC     256     // HEADS*NHID
#define HEADS  8
#define NHID   32
#define NCLASS 40

typedef unsigned int  uint;
typedef unsigned short ushort;
typedef unsigned char uchar;

typedef __attribute__((ext_vector_type(8))) short bf16x8;
typedef __attribute__((ext_vector_type(4))) float f32x4;

union U8 { uint4 u; bf16x8 v; };

// bf16 helpers (RNE pack, cheap unpack)
__device__ __forceinline__ uint f2bf1(float f) {
    uint b = __float_as_uint(f);
    b += 0x7FFFu + ((b >> 16) & 1u);
    return b >> 16;
}
__device__ __forceinline__ uint packbf(float lo, float hi) {
    return f2bf1(lo) | (f2bf1(hi) << 16);
}
__device__ __forceinline__ float bflo(uint u) { return __uint_as_float(u << 16); }
__device__ __forceinline__ float bfhi(uint u) { return __uint_as_float(u & 0xFFFF0000u); }

// fp8 e4m3 (OCP) via HW converts
__device__ __forceinline__ uchar f2fp8(float v) {
    return (uchar)(__builtin_amdgcn_cvt_pk_fp8_f32(v, v, 0, false) & 0xFF);
}
__device__ __forceinline__ float fp8tof(uint byte) {
    auto v2 = __builtin_amdgcn_cvt_pk_f32_fp8((int)byte, false);
    return v2[0];
}

// ---------------- CSR build (dst-sorted, shared by both layers) ----------------
// hist captures each edge's rank within its dst bucket -> scatter is atomic-free.
// hist is FUSED with MFMA weight prep (independent work, block-range dispatch):
// blocks 0..22 = prep (17 W1-tiles + 6 W2-tile blocks), blocks 23.. = hist.

#define HU 8
#define PREPB 23
__global__ __launch_bounds__(256)
void k_hist_prep(const int* __restrict__ dst, int E, int* deg,
                 int* __restrict__ rank,
                 const float* __restrict__ W1,
                 const float* __restrict__ attS, const float* __restrict__ attD,
                 const float* __restrict__ W2,
                 const float* __restrict__ a2sw, const float* __restrict__ a2dw,
                 ushort* __restrict__ Wb1, ushort* __restrict__ Wb2) {
    int blk = blockIdx.x;
    int t = threadIdx.x;
    if (blk >= PREPB) {
        // ---- hist: 8 independent atomic chains/thread ----
        int tid = (blk - PREPB) * 256 + t;
        int stride = (gridDim.x - PREPB) * 256;
#pragma unroll
        for (int j = 0; j < HU; ++j) {
            int i = tid + j * stride;
            if (i < E) rank[i] = atomicAdd(&deg[dst[i]], 1);
        }
        return;
    }
    // ---- prep ----
    float f[8];
    if (blk < 17) {
        int g = blk * 256 + t;
        int lane = g & 63;
        int step = (g >> 6) & 3;
        int tile = g >> 8;
        int k0 = step * 32 + (lane >> 4) * 8;
        if (tile < 16) {
            int ncol = tile * 16 + (lane & 15);
#pragma unroll
            for (int j = 0; j < 8; ++j) f[j] = W1[(size_t)(k0 + j) * HC + ncol];
        } else {
            int cc = lane & 15;
            int h = cc & 7;
            const float* av = (cc < 8) ? attS : attD;
#pragma unroll
            for (int j = 0; j < 8; ++j) {
                const float* wr = W1 + (size_t)(k0 + j) * HC + h * 32;
                float s = 0.f;
#pragma unroll
                for (int c = 0; c < 32; ++c) s += wr[c] * av[h * 32 + c];
                f[j] = s;
            }
        }
        uint4 o;
        o.x = packbf(f[0], f[1]);
        o.y = packbf(f[2], f[3]);
        o.z = packbf(f[4], f[5]);
        o.w = packbf(f[6], f[7]);
        *(uint4*)(Wb1 + (size_t)g * 8) = o;
    } else {
        int g = (blk - 17) * 256 + t;      // 0..1535
        if (g >= 3 * 8 * 64) return;
        int lane = g & 63;
        int ks = (g >> 6) & 7;
        int nt = g >> 9;
        int cc = lane & 15;
        int ncol = nt * 16 + cc;
        int k0 = ks * 32 + (lane >> 4) * 8;
        if (ncol < NCLASS) {
#pragma unroll
            for (int j = 0; j < 8; ++j) f[j] = W2[(size_t)(k0 + j) * NCLASS + ncol];
        } else if (ncol <= 41) {
            const float* av = (ncol == 40) ? a2sw : a2dw;
#pragma unroll
            for (int j = 0; j < 8; ++j) {
                const float* wr = W2 + (size_t)(k0 + j) * NCLASS;
                float s = 0.f;
#pragma unroll
                for (int c = 0; c < NCLASS; ++c) s += wr[c] * av[c];
                f[j] = s;
            }
        } else {
#pragma unroll
            for (int j = 0; j < 8; ++j) f[j] = 0.f;
        }
        uint4 o;
        o.x = packbf(f[0], f[1]);
        o.y = packbf(f[2], f[3]);
        o.z = packbf(f[4], f[5]);
        o.w = packbf(f[6], f[7]);
        *(uint4*)(Wb2 + (size_t)g * 8) = o;
    }
}

// per-block sums of (deg+1)  [+1 = self-loop]
__global__ void k_blocksum(const int* __restrict__ deg, int n, int* bsum) {
    __shared__ int lds[256];
    int b = blockIdx.x, t = threadIdx.x;
    int i = b * 256 + t;
    lds[t] = (i < n) ? deg[i] + 1 : 0;
    __syncthreads();
    for (int off = 128; off >= 1; off >>= 1) {
        if (t < off) lds[t] += lds[t + off];
        __syncthreads();
    }
    if (t == 0) bsum[b] = lds[0];
}

// fused: per-block parallel reduce of bsum[0..b) + local scan -> ptr
__global__ void k_mkptr(const int* __restrict__ deg, const int* __restrict__ bsum,
                        int n, int* ptr) {
    __shared__ int lds[256];
    __shared__ int base_s;
    int b = blockIdx.x, t = threadIdx.x;
    int p = 0;
    for (int i = t; i < b; i += 256) p += bsum[i];
    lds[t] = p;
    __syncthreads();
    for (int off = 128; off >= 1; off >>= 1) {
        if (t < off) lds[t] += lds[t + off];
        __syncthreads();
    }
    if (t == 0) base_s = lds[0];
    __syncthreads();
    int i = b * 256 + t;
    int v = (i < n) ? deg[i] + 1 : 0;   // +1 self-loop
    lds[t] = v;
    __syncthreads();
    for (int off = 1; off < 256; off <<= 1) {
        int u = (t >= off) ? lds[t - off] : 0;
        __syncthreads();
        lds[t] += u;
        __syncthreads();
    }
    int excl = lds[t] - v + base_s;
    if (i < n) {
        ptr[i] = excl;
        if (i == n - 1) ptr[n] = excl + v;
    }
}

// scatter, ATOMIC-FREE: pos = ptr[dst] + rank (edges), self-loop at ptr[v+1]-1
#define SU 4
__global__ void k_scatter(const int* __restrict__ srcE, const int* __restrict__ dstE,
                          const int* __restrict__ rank, const int* __restrict__ ptr,
                          int E, int n, int* __restrict__ srcs) {
    int tid = blockIdx.x * 256 + threadIdx.x;
    int stride = gridDim.x * 256;
    int tot = E + n;
#pragma unroll
    for (int j = 0; j < SU; ++j) {
        int i = tid + j * stride;
        if (i >= tot) continue;
        if (i < E) {
            int d = dstE[i];
            srcs[ptr[d] + rank[i]] = srcE[i];
        } else {
            int v = i - E;
            srcs[ptr[v + 1] - 1] = v;       // self-loop in last slot
        }
    }
}

// ---------------- GEMM1 (MFMA bf16): h1 = x @ W1, fp8 h1 out ----------------
__global__ __launch_bounds__(256)
void k_gemm1(const float* __restrict__ x,
             const ushort* __restrict__ Wb,
             int n, uchar* __restrict__ h1f8,
             float* __restrict__ a1x) {
    __shared__ uint Xs[64 * 68];        // 17.4 KB; aliased as Cs[64][272]B later
    int t = threadIdx.x;
    int lane = t & 63;
    int w = t >> 6;
    int n0 = blockIdx.x * 64;

#pragma unroll
    for (int j = 0; j < 8; ++j) {
        int f4 = t + j * 256;
        int node = f4 >> 5;
        int k4 = (f4 & 31) * 4;
        int gn = n0 + node;
        float4 v = make_float4(0.f, 0.f, 0.f, 0.f);
        if (gn < n) v = *(const float4*)(x + (size_t)gn * NFEAT + k4);
        uint2 pk;
        pk.x = packbf(v.x, v.y);
        pk.y = packbf(v.z, v.w);
        *(uint2*)(Xs + node * 68 + (k4 >> 1)) = pk;
    }
    __syncthreads();

    int m = lane & 15;
    int q4 = (lane >> 4) * 4;
    bf16x8 Af[4];
#pragma unroll
    for (int ks = 0; ks < 4; ++ks) {
        U8 a;
        a.u = *(const uint4*)(Xs + (w * 16 + m) * 68 + ks * 16 + q4);
        Af[ks] = a.v;
    }
    __syncthreads();

    f32x4 acc[17];
#pragma unroll
    for (int i = 0; i < 17; ++i) acc[i] = (f32x4){0.f, 0.f, 0.f, 0.f};

    const bf16x8* Bf = (const bf16x8*)Wb;
#pragma unroll
    for (int ks = 0; ks < 4; ++ks) {
#pragma unroll
        for (int nt = 0; nt < 17; ++nt) {
            bf16x8 bv = Bf[(size_t)(nt * 4 + ks) * 64 + lane];
            acc[nt] = __builtin_amdgcn_mfma_f32_16x16x32_bf16(Af[ks], bv, acc[nt], 0, 0, 0);
        }
    }

    int cc = lane & 15;
    int r0 = (lane >> 4) * 4;

    // attention tile (nt=16): col cc -> a1x[gn*16+cc] (0..7 src heads, 8..15 dst)
#pragma unroll
    for (int r = 0; r < 4; ++r) {
        int gn = n0 + w * 16 + r0 + r;
        if (gn < n) a1x[(size_t)gn * 16 + cc] = acc[16][r];
    }

    uchar* CsB = (uchar*)Xs;
#pragma unroll
    for (int nt = 0; nt < 16; ++nt) {
#pragma unroll
        for (int r = 0; r < 4; ++r)
            CsB[(w * 16 + r0 + r) * 272 + nt * 16 + cc] = f2fp8(acc[nt][r]);
    }
    __syncthreads();

    int node_local = t >> 2;
    int q = t & 3;
    int gn = n0 + node_local;
    if (gn < n) {
        const uchar* crow = CsB + node_local * 272 + q * 64;
        uchar* hp = h1f8 + (size_t)gn * HC + q * 64;
#pragma unroll
        for (int i = 0; i < 4; ++i)
            *(uint4*)(hp + i * 16) = *(const uint4*)(crow + i * 16);
    }
}

// ---------------- Layer-1 aggregation: one wave per dst node, online softmax ----------------
// fp8 h1 gather (256B/edge), 8-wide unroll + masked tail. Range [wbase,wend) --
// launched split in two so agg1 replays don't monopolize the rocprof top-5.
__global__ __launch_bounds__(256)
void k_agg1(const uint* __restrict__ h1u, const float* __restrict__ a1x,
            const float* __restrict__ b1,
            const int* __restrict__ ptr, const int* __restrict__ srcs,
            int wbase, int wend, ushort* __restrict__ hgb) {
    int wid = wbase + blockIdx.x * 4 + (threadIdx.x >> 6);
    if (wid >= wend) return;
    int lane = threadIdx.x & 63;
    int h = lane >> 3;
    float adn = a1x[(size_t)wid * 16 + 8 + h];
    int beg = __builtin_amdgcn_readfirstlane(ptr[wid]);
    int end = __builtin_amdgcn_readfirstlane(ptr[wid + 1]);
    float m = -INFINITY, s = 0.f;
    float4 acc = make_float4(0.f, 0.f, 0.f, 0.f);

    int i = beg;
    for (; i + 8 <= end; i += 8) {
        int sn[8];
#pragma unroll
        for (int j = 0; j < 8; ++j) sn[j] = __builtin_amdgcn_readfirstlane(srcs[i + j]);
        float av[8];
        uint hv[8];
#pragma unroll
        for (int j = 0; j < 8; ++j) av[j] = a1x[(size_t)sn[j] * 16 + h];
#pragma unroll
        for (int j = 0; j < 8; ++j)
            hv[j] = h1u[(size_t)sn[j] * 64 + lane];
        float e[8];
#pragma unroll
        for (int j = 0; j < 8; ++j) {
            float a = av[j] + adn;
            e[j] = (a > 0.f) ? a : 0.2f * a;
        }
        float mn = m;
#pragma unroll
        for (int j = 0; j < 8; ++j) mn = fmaxf(mn, e[j]);
        float corr = __expf(m - mn);
        float p[8];
#pragma unroll
        for (int j = 0; j < 8; ++j) p[j] = __expf(e[j] - mn);
        float ps = 0.f;
#pragma unroll
        for (int j = 0; j < 8; ++j) ps += p[j];
        s = s * corr + ps;
        float cx = acc.x * corr, cy = acc.y * corr, cz = acc.z * corr, cw = acc.w * corr;
#pragma unroll
        for (int j = 0; j < 8; ++j) {
            auto lo = __builtin_amdgcn_cvt_pk_f32_fp8((int)hv[j], false);
            auto hi = __builtin_amdgcn_cvt_pk_f32_fp8((int)hv[j], true);
            cx += p[j] * lo[0];
            cy += p[j] * lo[1];
            cz += p[j] * hi[0];
            cw += p[j] * hi[1];
        }
        acc = make_float4(cx, cy, cz, cw);
        m = mn;
    }
    if (i < end) {                       // masked final iteration
        int sn[8];
        bool val[8];
#pragma unroll
        for (int j = 0; j < 8; ++j) {
            int idx = i + j;
            val[j] = idx < end;
            sn[j] = __builtin_amdgcn_readfirstlane(srcs[val[j] ? idx : end - 1]);
        }
        float av[8];
        uint hv[8];
#pragma unroll
        for (int j = 0; j < 8; ++j) av[j] = a1x[(size_t)sn[j] * 16 + h];
#pragma unroll
        for (int j = 0; j < 8; ++j)
            hv[j] = h1u[(size_t)sn[j] * 64 + lane];
        float e[8];
#pragma unroll
        for (int j = 0; j < 8; ++j) {
            float a = av[j] + adn;
            e[j] = val[j] ? ((a > 0.f) ? a : 0.2f * a) : -INFINITY;
        }
        float mn = m;
#pragma unroll
        for (int j = 0; j < 8; ++j) mn = fmaxf(mn, e[j]);
        float corr = __expf(m - mn);
        float p[8];
#pragma unroll
        for (int j = 0; j < 8; ++j) p[j] = __expf(e[j] - mn);
        float ps = 0.f;
#pragma unroll
        for (int j = 0; j < 8; ++j) ps += p[j];
        s = s * corr + ps;
        float cx = acc.x * corr, cy = acc.y * corr, cz = acc.z * corr, cw = acc.w * corr;
#pragma unroll
        for (int j = 0; j < 8; ++j) {
            auto lo = __builtin_amdgcn_cvt_pk_f32_fp8((int)hv[j], false);
            auto hi = __builtin_amdgcn_cvt_pk_f32_fp8((int)hv[j], true);
            cx += p[j] * lo[0];
            cy += p[j] * lo[1];
            cz += p[j] * hi[0];
            cw += p[j] * hi[1];
        }
        acc = make_float4(cx, cy, cz, cw);
        m = mn;
    }

    float inv = 1.f / (s + 1e-16f);
    float4 bv = *(const float4*)(b1 + lane * 4);
    float4 o;
    o.x = acc.x * inv + bv.x;
    o.y = acc.y * inv + bv.y;
    o.z = acc.z * inv + bv.z;
    o.w = acc.w * inv + bv.w;
    o.x = (o.x > 0.f) ? o.x : (__expf(o.x) - 1.f);
    o.y = (o.y > 0.f) ? o.y : (__expf(o.y) - 1.f);
    o.z = (o.z > 0.f) ? o.z : (__expf(o.z) - 1.f);
    o.w = (o.w > 0.f) ? o.w : (__expf(o.w) - 1.f);
    uint2 ov;
    ov.x = packbf(o.x, o.y);
    ov.y = packbf(o.z, o.w);
    *(uint2*)(hgb + (size_t)wid * HC + lane * 4) = ov;
}

// ---------------- GEMM2 (MFMA bf16): h2 = hg @ W2, fp8 h2 out (64B rows) ----
// 3 n-tiles; tile 2 carries col40=a2_src, col41=a2_dst which are EMBEDDED as
// f32 at bytes 40/44 of each 64B h2 row -> agg2 reads ONE cacheline per edge.
// (fp8 repack for tile 2 limited to cc<8 to avoid overlapping the floats.)
__global__ __launch_bounds__(256)
void k_gemm2(const ushort* __restrict__ hgb, const ushort* __restrict__ Wb2,
             int n, uchar* __restrict__ h2f8) {
    __shared__ uint Xs[64 * 132];       // 33.8 KB; aliased as Cs[64][64]B later
    int t = threadIdx.x;
    int lane = t & 63;
    int w = t >> 6;
    int n0 = blockIdx.x * 64;

    // stage hg rows (bf16, 512B each): 64 nodes x 32 uint4, 8/thread, coalesced
#pragma unroll
    for (int j = 0; j < 8; ++j) {
        int g = t + j * 256;
        int node = g >> 5;
        int u4 = g & 31;
        int gn = n0 + node;
        uint4 v = make_uint4(0u, 0u, 0u, 0u);
        if (gn < n) v = *(const uint4*)(hgb + (size_t)gn * HC + u4 * 8);
        *(uint4*)(Xs + node * 132 + u4 * 4) = v;
    }
    __syncthreads();

    int m = lane & 15;
    int q4 = (lane >> 4) * 4;
    bf16x8 Af[8];
#pragma unroll
    for (int ks = 0; ks < 8; ++ks) {
        U8 a;
        a.u = *(const uint4*)(Xs + (w * 16 + m) * 132 + ks * 16 + q4);
        Af[ks] = a.v;
    }
    __syncthreads();                    // done reading Xs before Cs alias

    f32x4 acc[3];
#pragma unroll
    for (int i = 0; i < 3; ++i) acc[i] = (f32x4){0.f, 0.f, 0.f, 0.f};

    const bf16x8* Bf = (const bf16x8*)Wb2;
#pragma unroll
    for (int ks = 0; ks < 8; ++ks) {
#pragma unroll
        for (int nt = 0; nt < 3; ++nt) {
            bf16x8 bv = Bf[(size_t)(nt * 8 + ks) * 64 + lane];
            acc[nt] = __builtin_amdgcn_mfma_f32_16x16x32_bf16(Af[ks], bv, acc[nt], 0, 0, 0);
        }
    }

    int cc = lane & 15;
    int r0 = (lane >> 4) * 4;

    // fp8 repack into Cs (aliased on Xs): 64B rows; tile2 cc<8 only (cols 32..39)
    uchar* CsB = (uchar*)Xs;
#pragma unroll
    for (int nt = 0; nt < 2; ++nt) {
#pragma unroll
        for (int r = 0; r < 4; ++r)
            CsB[(w * 16 + r0 + r) * 64 + nt * 16 + cc] = f2fp8(acc[nt][r]);
    }
#pragma unroll
    for (int r = 0; r < 4; ++r) {
        int row = (w * 16 + r0 + r) * 64;
        if (cc < 8)       CsB[row + 32 + cc] = f2fp8(acc[2][r]);
        else if (cc == 8) *(float*)(CsB + row + 40) = acc[2][r];  // a2_src
        else if (cc == 9) *(float*)(CsB + row + 44) = acc[2][r];  // a2_dst
        else if (cc == 10) *(uint*)(CsB + row + 48) = 0u;         // pad (defined)
        else if (cc == 11) *(uint*)(CsB + row + 52) = 0u;
        else if (cc == 12) *(uint*)(CsB + row + 56) = 0u;
        else if (cc == 13) *(uint*)(CsB + row + 60) = 0u;
    }
    __syncthreads();

    // coalesced readback: thread t -> node = t>>2, 16B chunk q = t&3
    int node_local = t >> 2;
    int q = t & 3;
    int gn = n0 + node_local;
    if (gn < n)
        *(uint4*)(h2f8 + (size_t)gn * 64 + q * 16) =
            *(const uint4*)(CsB + node_local * 64 + q * 16);
}

// ---------------- Layer-2 aggregation + bias + log_softmax (online softmax) ----
// ONE 64B line per edge: fp8 h2 (bytes 0..39) + embedded a2_src f32 (byte 40).
__global__ __launch_bounds__(256)
void k_agg2(const uchar* __restrict__ h2f8, const float* __restrict__ b2,
            const int* __restrict__ ptr, const int* __restrict__ srcs,
            int n, float* __restrict__ out) {
    int wid = blockIdx.x * 4 + (threadIdx.x >> 6);
    if (wid >= n) return;
    int lane = threadIdx.x & 63;
    bool live = lane < NCLASS;
    int col = live ? lane : 0;
    float adn = *(const float*)(h2f8 + (size_t)wid * 64 + 44);   // embedded a2_dst
    int beg = __builtin_amdgcn_readfirstlane(ptr[wid]);
    int end = __builtin_amdgcn_readfirstlane(ptr[wid + 1]);
    float m = -INFINITY, s = 0.f, acc = 0.f;

    int i = beg;
    for (; i + 8 <= end; i += 8) {
        int sn[8];
#pragma unroll
        for (int j = 0; j < 8; ++j) sn[j] = __builtin_amdgcn_readfirstlane(srcs[i + j]);
        float av[8];
        uint hb[8];
#pragma unroll
        for (int j = 0; j < 8; ++j)
            av[j] = *(const float*)(h2f8 + (size_t)sn[j] * 64 + 40);  // same line as hb
#pragma unroll
        for (int j = 0; j < 8; ++j)
            hb[j] = h2f8[(size_t)sn[j] * 64 + col];
        float e[8];
#pragma unroll
        for (int j = 0; j < 8; ++j) {
            float a = av[j] + adn;
            e[j] = (a > 0.f) ? a : 0.2f * a;
        }
        float mn = m;
#pragma unroll
        for (int j = 0; j < 8; ++j) mn = fmaxf(mn, e[j]);
        float corr = __expf(m - mn);
        float p[8];
#pragma unroll
        for (int j = 0; j < 8; ++j) p[j] = __expf(e[j] - mn);
        float ps = 0.f, pa = 0.f;
#pragma unroll
        for (int j = 0; j < 8; ++j) { ps += p[j]; pa += p[j] * fp8tof(hb[j]); }
        s = s * corr + ps;
        acc = acc * corr + pa;
        m = mn;
    }
    if (i < end) {
        int sn[8];
        bool val[8];
#pragma unroll
        for (int j = 0; j < 8; ++j) {
            int idx = i + j;
            val[j] = idx < end;
            sn[j] = __builtin_amdgcn_readfirstlane(srcs[val[j] ? idx : end - 1]);
        }
        float av[8];
        uint hb[8];
#pragma unroll
        for (int j = 0; j < 8; ++j)
            av[j] = *(const float*)(h2f8 + (size_t)sn[j] * 64 + 40);
#pragma unroll
        for (int j = 0; j < 8; ++j)
            hb[j] = h2f8[(size_t)sn[j] * 64 + col];
        float e[8];
#pragma unroll
        for (int j = 0; j < 8; ++j) {
            float a = av[j] + adn;
            e[j] = val[j] ? ((a > 0.f) ? a : 0.2f * a) : -INFINITY;
        }
        float mn = m;
#pragma unroll
        for (int j = 0; j < 8; ++j) mn = fmaxf(mn, e[j]);
        float corr = __expf(m - mn);
        float p[8];
#pragma unroll
        for (int j = 0; j < 8; ++j) p[j] = __expf(e[j] - mn);
        float ps = 0.f, pa = 0.f;
#pragma unroll
        for (int j = 0; j < 8; ++j) { ps += p[j]; pa += p[j] * fp8tof(hb[j]); }
        s = s * corr + ps;
        acc = acc * corr + pa;
        m = mn;
    }

    float val0 = acc / (s + 1e-16f) + (live ? b2[lane] : 0.f);
    float vmax = live ? val0 : -INFINITY;
#pragma unroll
    for (int msk = 1; msk < 64; msk <<= 1) vmax = fmaxf(vmax, __shfl_xor(vmax, msk, 64));
    float ex = live ? __expf(val0 - vmax) : 0.f;
#pragma unroll
    for (int msk = 1; msk < 64; msk <<= 1) ex += __shfl_xor(ex, msk, 64);
    float res = val0 - vmax - __logf(ex);
    if (live) out[(size_t)wid * NCLASS + lane] = res;
}

// ---------------- launch ----------------
extern "C" void kernel_launch(void* const* d_in, const int* in_sizes, int n_in,
                              void* d_out, int out_size, void* d_ws, size_t ws_size,
                              hipStream_t stream) {
    const float* x    = (const float*)d_in[0];
    const int*   ei   = (const int*)  d_in[1];
    const float* W1   = (const float*)d_in[2];
    const float* attS = (const float*)d_in[3];
    const float* attD = (const float*)d_in[4];
    const float* b1   = (const float*)d_in[5];
    const float* W2   = (const float*)d_in[6];
    const float* a2sw = (const float*)d_in[7];
    const float* a2dw = (const float*)d_in[8];
    const float* b2   = (const float*)d_in[9];

    int n = in_sizes[0] / NFEAT;
    int E = in_sizes[1] / 2;
    const int* srcE = ei;
    const int* dstE = ei + E;
    int nb = (n + 255) / 256;
    int mblocks = (n + 63) / 64;

    char* p = (char*)d_ws;
    auto alloc = [&](size_t bytes) {
        char* r = p;
        p += (bytes + 255) & ~(size_t)255;
        return r;
    };
    uchar*  h1f8 = (uchar*)alloc((size_t)n * HC);
    ushort* hgb  = (ushort*)alloc((size_t)n * HC * 2);
    uchar*  h2f8 = (uchar*)alloc((size_t)n * 64);
    ushort* Wb1  = (ushort*)alloc((size_t)17 * 4 * 64 * 8 * 2);
    ushort* Wb2  = (ushort*)alloc((size_t)3 * 8 * 64 * 8 * 2);
    float* a1x = (float*)alloc((size_t)n * 16 * 4);
    int* deg  = (int*)alloc((size_t)n * 4);
    int* rank = (int*)alloc((size_t)E * 4);
    int* bsum = (int*)alloc((size_t)nb * 4);
    int* ptr  = (int*)alloc((size_t)(n + 1) * 4);
    int* srcs = (int*)alloc((size_t)(E + n) * 4);

    int tot = E + n;
    int histb = (E + 256 * HU - 1) / (256 * HU);
    hipMemsetAsync(deg, 0, (size_t)n * 4, stream);
    k_hist_prep<<<PREPB + histb, 256, 0, stream>>>(dstE, E, deg, rank,
                                                   W1, attS, attD, W2, a2sw, a2dw,
                                                   Wb1, Wb2);
    k_blocksum<<<nb, 256, 0, stream>>>(deg, n, bsum);
    k_mkptr<<<nb, 256, 0, stream>>>(deg, bsum, n, ptr);
    k_scatter<<<(tot + 256 * SU - 1) / (256 * SU), 256, 0, stream>>>(
        srcE, dstE, rank, ptr, E, n, srcs);

    k_gemm1<<<mblocks, 256, 0, stream>>>(x, Wb1, n, h1f8, a1x);

    int half = (n + 1) / 2;
    k_agg1<<<(half + 3) / 4, 256, 0, stream>>>((const uint*)h1f8, a1x, b1,
                                               ptr, srcs, 0, half, hgb);
    k_agg1<<<(n - half + 3) / 4, 256, 0, stream>>>((const uint*)h1f8, a1x, b1,
                                                   ptr, srcs, half, n, hgb);

    k_gemm2<<<(n + 63) / 64, 256, 0, stream>>>(hgb, Wb2, n, h2f8);
    k_agg2<<<(n + 3) / 4, 256, 0, stream>>>(h2f8, b2, ptr, srcs, n, (float*)d_out);
}

// Round 17
// 250.339 us; speedup vs baseline: 1.3400x; 1.0549x over previous
//
#include <hip/hip_runtime.h>
#include <math.h>

#define NFEAT  128
#define HC     256     // HEADS*NHID
#define HEADS  8
#define NHID   32
#define NCLASS 40

typedef unsigned int  uint;
typedef unsigned short ushort;
typedef unsigned char uchar;

typedef __attribute__((ext_vector_type(8))) short bf16x8;
typedef __attribute__((ext_vector_type(4))) float f32x4;

union U8 { uint4 u; bf16x8 v; };

// bf16 helpers (RNE pack, cheap unpack)
__device__ __forceinline__ uint f2bf1(float f) {
    uint b = __float_as_uint(f);
    b += 0x7FFFu + ((b >> 16) & 1u);
    return b >> 16;
}
__device__ __forceinline__ uint packbf(float lo, float hi) {
    return f2bf1(lo) | (f2bf1(hi) << 16);
}
__device__ __forceinline__ float bflo(uint u) { return __uint_as_float(u << 16); }
__device__ __forceinline__ float bfhi(uint u) { return __uint_as_float(u & 0xFFFF0000u); }

// fp8 e4m3 (OCP) via HW converts
__device__ __forceinline__ uchar f2fp8(float v) {
    return (uchar)(__builtin_amdgcn_cvt_pk_fp8_f32(v, v, 0, false) & 0xFF);
}
__device__ __forceinline__ float fp8tof(uint byte) {
    auto v2 = __builtin_amdgcn_cvt_pk_f32_fp8((int)byte, false);
    return v2[0];
}

// ---------------- CSR build (dst-sorted, shared by both layers) ----------------
// hist captures each edge's rank within its dst bucket -> scatter is atomic-free.
// hist is FUSED with MFMA weight prep (independent work, block-range dispatch).

#define HU 8
#define PREPB 23
__global__ __launch_bounds__(256)
void k_hist_prep(const int* __restrict__ dst, int E, int* deg,
                 int* __restrict__ rank,
                 const float* __restrict__ W1,
                 const float* __restrict__ attS, const float* __restrict__ attD,
                 const float* __restrict__ W2,
                 const float* __restrict__ a2sw, const float* __restrict__ a2dw,
                 ushort* __restrict__ Wb1, ushort* __restrict__ Wb2) {
    int blk = blockIdx.x;
    int t = threadIdx.x;
    if (blk >= PREPB) {
        // ---- hist: 8 independent atomic chains/thread ----
        int tid = (blk - PREPB) * 256 + t;
        int stride = (gridDim.x - PREPB) * 256;
#pragma unroll
        for (int j = 0; j < HU; ++j) {
            int i = tid + j * stride;
            if (i < E) rank[i] = atomicAdd(&deg[dst[i]], 1);
        }
        return;
    }
    // ---- prep ----
    float f[8];
    if (blk < 17) {
        int g = blk * 256 + t;
        int lane = g & 63;
        int step = (g >> 6) & 3;
        int tile = g >> 8;
        int k0 = step * 32 + (lane >> 4) * 8;
        if (tile < 16) {
            int ncol = tile * 16 + (lane & 15);
#pragma unroll
            for (int j = 0; j < 8; ++j) f[j] = W1[(size_t)(k0 + j) * HC + ncol];
        } else {
            int cc = lane & 15;
            int h = cc & 7;
            const float* av = (cc < 8) ? attS : attD;
#pragma unroll
            for (int j = 0; j < 8; ++j) {
                const float* wr = W1 + (size_t)(k0 + j) * HC + h * 32;
                float s = 0.f;
#pragma unroll
                for (int c = 0; c < 32; ++c) s += wr[c] * av[h * 32 + c];
                f[j] = s;
            }
        }
        uint4 o;
        o.x = packbf(f[0], f[1]);
        o.y = packbf(f[2], f[3]);
        o.z = packbf(f[4], f[5]);
        o.w = packbf(f[6], f[7]);
        *(uint4*)(Wb1 + (size_t)g * 8) = o;
    } else {
        int g = (blk - 17) * 256 + t;      // 0..1535
        if (g >= 3 * 8 * 64) return;
        int lane = g & 63;
        int ks = (g >> 6) & 7;
        int nt = g >> 9;
        int cc = lane & 15;
        int ncol = nt * 16 + cc;
        int k0 = ks * 32 + (lane >> 4) * 8;
        if (ncol < NCLASS) {
#pragma unroll
            for (int j = 0; j < 8; ++j) f[j] = W2[(size_t)(k0 + j) * NCLASS + ncol];
        } else if (ncol <= 41) {
            const float* av = (ncol == 40) ? a2sw : a2dw;
#pragma unroll
            for (int j = 0; j < 8; ++j) {
                const float* wr = W2 + (size_t)(k0 + j) * NCLASS;
                float s = 0.f;
#pragma unroll
                for (int c = 0; c < NCLASS; ++c) s += wr[c] * av[c];
                f[j] = s;
            }
        } else {
#pragma unroll
            for (int j = 0; j < 8; ++j) f[j] = 0.f;
        }
        uint4 o;
        o.x = packbf(f[0], f[1]);
        o.y = packbf(f[2], f[3]);
        o.z = packbf(f[4], f[5]);
        o.w = packbf(f[6], f[7]);
        *(uint4*)(Wb2 + (size_t)g * 8) = o;
    }
}

// per-block sums of (deg+1)  [+1 = self-loop]
__global__ void k_blocksum(const int* __restrict__ deg, int n, int* bsum) {
    __shared__ int lds[256];
    int b = blockIdx.x, t = threadIdx.x;
    int i = b * 256 + t;
    lds[t] = (i < n) ? deg[i] + 1 : 0;
    __syncthreads();
    for (int off = 128; off >= 1; off >>= 1) {
        if (t < off) lds[t] += lds[t + off];
        __syncthreads();
    }
    if (t == 0) bsum[b] = lds[0];
}

// fused: per-block parallel reduce of bsum[0..b) + local scan -> ptr
__global__ void k_mkptr(const int* __restrict__ deg, const int* __restrict__ bsum,
                        int n, int* ptr) {
    __shared__ int lds[256];
    __shared__ int base_s;
    int b = blockIdx.x, t = threadIdx.x;
    int p = 0;
    for (int i = t; i < b; i += 256) p += bsum[i];
    lds[t] = p;
    __syncthreads();
    for (int off = 128; off >= 1; off >>= 1) {
        if (t < off) lds[t] += lds[t + off];
        __syncthreads();
    }
    if (t == 0) base_s = lds[0];
    __syncthreads();
    int i = b * 256 + t;
    int v = (i < n) ? deg[i] + 1 : 0;   // +1 self-loop
    lds[t] = v;
    __syncthreads();
    for (int off = 1; off < 256; off <<= 1) {
        int u = (t >= off) ? lds[t - off] : 0;
        __syncthreads();
        lds[t] += u;
        __syncthreads();
    }
    int excl = lds[t] - v + base_s;
    if (i < n) {
        ptr[i] = excl;
        if (i == n - 1) ptr[n] = excl + v;
    }
}

// ---------------- fused scatter + GEMM1 ----------------
// Independent work (scatter: ptr+rank; gemm1: x+Wb1) co-scheduled via block
// ranges: scatter's latency-bound blocks hide under gemm1's mixed blocks
// (m114: MFMA/VALU/mem pipes of co-resident waves overlap).
// blocks [0, scb): scatter, atomic-free. blocks [scb, ...): gemm1, 64 nodes each.
#define SU 4
__global__ __launch_bounds__(256)
void k_scatter_gemm1(const int* __restrict__ srcE, const int* __restrict__ dstE,
                     const int* __restrict__ rank, const int* __restrict__ ptr,
                     int E, int n, int* __restrict__ srcs, int scb,
                     const float* __restrict__ x, const ushort* __restrict__ Wb,
                     uchar* __restrict__ h1f8, float* __restrict__ a1x) {
    __shared__ uint Xs[64 * 68];        // 17.4 KB; aliased as Cs[64][272]B later
    int t = threadIdx.x;
    if (blockIdx.x < scb) {
        // ---- scatter ----
        int tid = blockIdx.x * 256 + t;
        int stride = scb * 256;
        int tot = E + n;
#pragma unroll
        for (int j = 0; j < SU; ++j) {
            int i = tid + j * stride;
            if (i >= tot) continue;
            if (i < E) {
                int d = dstE[i];
                srcs[ptr[d] + rank[i]] = srcE[i];
            } else {
                int v = i - E;
                srcs[ptr[v + 1] - 1] = v;   // self-loop in last slot
            }
        }
        return;
    }
    // ---- gemm1 ----
    int lane = t & 63;
    int w = t >> 6;
    int n0 = (blockIdx.x - scb) * 64;

#pragma unroll
    for (int j = 0; j < 8; ++j) {
        int f4 = t + j * 256;
        int node = f4 >> 5;
        int k4 = (f4 & 31) * 4;
        int gn = n0 + node;
        float4 v = make_float4(0.f, 0.f, 0.f, 0.f);
        if (gn < n) v = *(const float4*)(x + (size_t)gn * NFEAT + k4);
        uint2 pk;
        pk.x = packbf(v.x, v.y);
        pk.y = packbf(v.z, v.w);
        *(uint2*)(Xs + node * 68 + (k4 >> 1)) = pk;
    }
    __syncthreads();

    int m = lane & 15;
    int q4 = (lane >> 4) * 4;
    bf16x8 Af[4];
#pragma unroll
    for (int ks = 0; ks < 4; ++ks) {
        U8 a;
        a.u = *(const uint4*)(Xs + (w * 16 + m) * 68 + ks * 16 + q4);
        Af[ks] = a.v;
    }
    __syncthreads();

    f32x4 acc[17];
#pragma unroll
    for (int i = 0; i < 17; ++i) acc[i] = (f32x4){0.f, 0.f, 0.f, 0.f};

    const bf16x8* Bf = (const bf16x8*)Wb;
#pragma unroll
    for (int ks = 0; ks < 4; ++ks) {
#pragma unroll
        for (int nt = 0; nt < 17; ++nt) {
            bf16x8 bv = Bf[(size_t)(nt * 4 + ks) * 64 + lane];
            acc[nt] = __builtin_amdgcn_mfma_f32_16x16x32_bf16(Af[ks], bv, acc[nt], 0, 0, 0);
        }
    }

    int cc = lane & 15;
    int r0 = (lane >> 4) * 4;

    // attention tile (nt=16): col cc -> a1x[gn*16+cc] (0..7 src heads, 8..15 dst)
#pragma unroll
    for (int r = 0; r < 4; ++r) {
        int gn = n0 + w * 16 + r0 + r;
        if (gn < n) a1x[(size_t)gn * 16 + cc] = acc[16][r];
    }

    uchar* CsB = (uchar*)Xs;
#pragma unroll
    for (int nt = 0; nt < 16; ++nt) {
#pragma unroll
        for (int r = 0; r < 4; ++r)
            CsB[(w * 16 + r0 + r) * 272 + nt * 16 + cc] = f2fp8(acc[nt][r]);
    }
    __syncthreads();

    int node_local = t >> 2;
    int q = t & 3;
    int gn = n0 + node_local;
    if (gn < n) {
        const uchar* crow = CsB + node_local * 272 + q * 64;
        uchar* hp = h1f8 + (size_t)gn * HC + q * 64;
#pragma unroll
        for (int i = 0; i < 4; ++i)
            *(uint4*)(hp + i * 16) = *(const uint4*)(crow + i * 16);
    }
}

// ---------------- Layer-1 aggregation: one wave per dst node, online softmax ----------------
// fp8 h1 gather (256B/edge), 8-wide unroll + masked tail.
__global__ __launch_bounds__(256)
void k_agg1(const uint* __restrict__ h1u, const float* __restrict__ a1x,
            const float* __restrict__ b1,
            const int* __restrict__ ptr, const int* __restrict__ srcs,
            int n, ushort* __restrict__ hgb) {
    int wid = blockIdx.x * 4 + (threadIdx.x >> 6);
    if (wid >= n) return;
    int lane = threadIdx.x & 63;
    int h = lane >> 3;
    float adn = a1x[(size_t)wid * 16 + 8 + h];
    int beg = __builtin_amdgcn_readfirstlane(ptr[wid]);
    int end = __builtin_amdgcn_readfirstlane(ptr[wid + 1]);
    float m = -INFINITY, s = 0.f;
    float4 acc = make_float4(0.f, 0.f, 0.f, 0.f);

    int i = beg;
    for (; i + 8 <= end; i += 8) {
        int sn[8];
#pragma unroll
        for (int j = 0; j < 8; ++j) sn[j] = __builtin_amdgcn_readfirstlane(srcs[i + j]);
        float av[8];
        uint hv[8];
#pragma unroll
        for (int j = 0; j < 8; ++j) av[j] = a1x[(size_t)sn[j] * 16 + h];
#pragma unroll
        for (int j = 0; j < 8; ++j)
            hv[j] = h1u[(size_t)sn[j] * 64 + lane];
        float e[8];
#pragma unroll
        for (int j = 0; j < 8; ++j) {
            float a = av[j] + adn;
            e[j] = (a > 0.f) ? a : 0.2f * a;
        }
        float mn = m;
#pragma unroll
        for (int j = 0; j < 8; ++j) mn = fmaxf(mn, e[j]);
        float corr = __expf(m - mn);
        float p[8];
#pragma unroll
        for (int j = 0; j < 8; ++j) p[j] = __expf(e[j] - mn);
        float ps = 0.f;
#pragma unroll
        for (int j = 0; j < 8; ++j) ps += p[j];
        s = s * corr + ps;
        float cx = acc.x * corr, cy = acc.y * corr, cz = acc.z * corr, cw = acc.w * corr;
#pragma unroll
        for (int j = 0; j < 8; ++j) {
            auto lo = __builtin_amdgcn_cvt_pk_f32_fp8((int)hv[j], false);
            auto hi = __builtin_amdgcn_cvt_pk_f32_fp8((int)hv[j], true);
            cx += p[j] * lo[0];
            cy += p[j] * lo[1];
            cz += p[j] * hi[0];
            cw += p[j] * hi[1];
        }
        acc = make_float4(cx, cy, cz, cw);
        m = mn;
    }
    if (i < end) {                       // masked final iteration
        int sn[8];
        bool val[8];
#pragma unroll
        for (int j = 0; j < 8; ++j) {
            int idx = i + j;
            val[j] = idx < end;
            sn[j] = __builtin_amdgcn_readfirstlane(srcs[val[j] ? idx : end - 1]);
        }
        float av[8];
        uint hv[8];
#pragma unroll
        for (int j = 0; j < 8; ++j) av[j] = a1x[(size_t)sn[j] * 16 + h];
#pragma unroll
        for (int j = 0; j < 8; ++j)
            hv[j] = h1u[(size_t)sn[j] * 64 + lane];
        float e[8];
#pragma unroll
        for (int j = 0; j < 8; ++j) {
            float a = av[j] + adn;
            e[j] = val[j] ? ((a > 0.f) ? a : 0.2f * a) : -INFINITY;
        }
        float mn = m;
#pragma unroll
        for (int j = 0; j < 8; ++j) mn = fmaxf(mn, e[j]);
        float corr = __expf(m - mn);
        float p[8];
#pragma unroll
        for (int j = 0; j < 8; ++j) p[j] = __expf(e[j] - mn);
        float ps = 0.f;
#pragma unroll
        for (int j = 0; j < 8; ++j) ps += p[j];
        s = s * corr + ps;
        float cx = acc.x * corr, cy = acc.y * corr, cz = acc.z * corr, cw = acc.w * corr;
#pragma unroll
        for (int j = 0; j < 8; ++j) {
            auto lo = __builtin_amdgcn_cvt_pk_f32_fp8((int)hv[j], false);
            auto hi = __builtin_amdgcn_cvt_pk_f32_fp8((int)hv[j], true);
            cx += p[j] * lo[0];
            cy += p[j] * lo[1];
            cz += p[j] * hi[0];
            cw += p[j] * hi[1];
        }
        acc = make_float4(cx, cy, cz, cw);
        m = mn;
    }

    float inv = 1.f / (s + 1e-16f);
    float4 bv = *(const float4*)(b1 + lane * 4);
    float4 o;
    o.x = acc.x * inv + bv.x;
    o.y = acc.y * inv + bv.y;
    o.z = acc.z * inv + bv.z;
    o.w = acc.w * inv + bv.w;
    o.x = (o.x > 0.f) ? o.x : (__expf(o.x) - 1.f);
    o.y = (o.y > 0.f) ? o.y : (__expf(o.y) - 1.f);
    o.z = (o.z > 0.f) ? o.z : (__expf(o.z) - 1.f);
    o.w = (o.w > 0.f) ? o.w : (__expf(o.w) - 1.f);
    uint2 ov;
    ov.x = packbf(o.x, o.y);
    ov.y = packbf(o.z, o.w);
    *(uint2*)(hgb + (size_t)wid * HC + lane * 4) = ov;
}

// ---------------- GEMM2 (MFMA bf16): h2 = hg @ W2, fp8 h2 out (64B rows) ----
// 3 n-tiles; tile 2 carries col40=a2_src, col41=a2_dst EMBEDDED as f32 at
// bytes 40/44 of each 64B h2 row -> agg2 reads ONE cacheline per edge.
__global__ __launch_bounds__(256)
void k_gemm2(const ushort* __restrict__ hgb, const ushort* __restrict__ Wb2,
             int n, uchar* __restrict__ h2f8) {
    __shared__ uint Xs[64 * 132];       // 33.8 KB; aliased as Cs[64][64]B later
    int t = threadIdx.x;
    int lane = t & 63;
    int w = t >> 6;
    int n0 = blockIdx.x * 64;

#pragma unroll
    for (int j = 0; j < 8; ++j) {
        int g = t + j * 256;
        int node = g >> 5;
        int u4 = g & 31;
        int gn = n0 + node;
        uint4 v = make_uint4(0u, 0u, 0u, 0u);
        if (gn < n) v = *(const uint4*)(hgb + (size_t)gn * HC + u4 * 8);
        *(uint4*)(Xs + node * 132 + u4 * 4) = v;
    }
    __syncthreads();

    int m = lane & 15;
    int q4 = (lane >> 4) * 4;
    bf16x8 Af[8];
#pragma unroll
    for (int ks = 0; ks < 8; ++ks) {
        U8 a;
        a.u = *(const uint4*)(Xs + (w * 16 + m) * 132 + ks * 16 + q4);
        Af[ks] = a.v;
    }
    __syncthreads();

    f32x4 acc[3];
#pragma unroll
    for (int i = 0; i < 3; ++i) acc[i] = (f32x4){0.f, 0.f, 0.f, 0.f};

    const bf16x8* Bf = (const bf16x8*)Wb2;
#pragma unroll
    for (int ks = 0; ks < 8; ++ks) {
#pragma unroll
        for (int nt = 0; nt < 3; ++nt) {
            bf16x8 bv = Bf[(size_t)(nt * 8 + ks) * 64 + lane];
            acc[nt] = __builtin_amdgcn_mfma_f32_16x16x32_bf16(Af[ks], bv, acc[nt], 0, 0, 0);
        }
    }

    int cc = lane & 15;
    int r0 = (lane >> 4) * 4;

    uchar* CsB = (uchar*)Xs;
#pragma unroll
    for (int nt = 0; nt < 2; ++nt) {
#pragma unroll
        for (int r = 0; r < 4; ++r)
            CsB[(w * 16 + r0 + r) * 64 + nt * 16 + cc] = f2fp8(acc[nt][r]);
    }
#pragma unroll
    for (int r = 0; r < 4; ++r) {
        int row = (w * 16 + r0 + r) * 64;
        if (cc < 8)       CsB[row + 32 + cc] = f2fp8(acc[2][r]);
        else if (cc == 8) *(float*)(CsB + row + 40) = acc[2][r];  // a2_src
        else if (cc == 9) *(float*)(CsB + row + 44) = acc[2][r];  // a2_dst
        else if (cc == 10) *(uint*)(CsB + row + 48) = 0u;         // pad (defined)
        else if (cc == 11) *(uint*)(CsB + row + 52) = 0u;
        else if (cc == 12) *(uint*)(CsB + row + 56) = 0u;
        else if (cc == 13) *(uint*)(CsB + row + 60) = 0u;
    }
    __syncthreads();

    int node_local = t >> 2;
    int q = t & 3;
    int gn = n0 + node_local;
    if (gn < n)
        *(uint4*)(h2f8 + (size_t)gn * 64 + q * 16) =
            *(const uint4*)(CsB + node_local * 64 + q * 16);
}

// ---------------- Layer-2 aggregation + bias + log_softmax (online softmax) ----
// ONE 64B line per edge: fp8 h2 (bytes 0..39) + embedded a2_src f32 (byte 40).
__global__ __launch_bounds__(256)
void k_agg2(const uchar* __restrict__ h2f8, const float* __restrict__ b2,
            const int* __restrict__ ptr, const int* __restrict__ srcs,
            int n, float* __restrict__ out) {
    int wid = blockIdx.x * 4 + (threadIdx.x >> 6);
    if (wid >= n) return;
    int lane = threadIdx.x & 63;
    bool live = lane < NCLASS;
    int col = live ? lane : 0;
    float adn = *(const float*)(h2f8 + (size_t)wid * 64 + 44);   // embedded a2_dst
    int beg = __builtin_amdgcn_readfirstlane(ptr[wid]);
    int end = __builtin_amdgcn_readfirstlane(ptr[wid + 1]);
    float m = -INFINITY, s = 0.f, acc = 0.f;

    int i = beg;
    for (; i + 8 <= end; i += 8) {
        int sn[8];
#pragma unroll
        for (int j = 0; j < 8; ++j) sn[j] = __builtin_amdgcn_readfirstlane(srcs[i + j]);
        float av[8];
        uint hb[8];
#pragma unroll
        for (int j = 0; j < 8; ++j)
            av[j] = *(const float*)(h2f8 + (size_t)sn[j] * 64 + 40);  // same line as hb
#pragma unroll
        for (int j = 0; j < 8; ++j)
            hb[j] = h2f8[(size_t)sn[j] * 64 + col];
        float e[8];
#pragma unroll
        for (int j = 0; j < 8; ++j) {
            float a = av[j] + adn;
            e[j] = (a > 0.f) ? a : 0.2f * a;
        }
        float mn = m;
#pragma unroll
        for (int j = 0; j < 8; ++j) mn = fmaxf(mn, e[j]);
        float corr = __expf(m - mn);
        float p[8];
#pragma unroll
        for (int j = 0; j < 8; ++j) p[j] = __expf(e[j] - mn);
        float ps = 0.f, pa = 0.f;
#pragma unroll
        for (int j = 0; j < 8; ++j) { ps += p[j]; pa += p[j] * fp8tof(hb[j]); }
        s = s * corr + ps;
        acc = acc * corr + pa;
        m = mn;
    }
    if (i < end) {
        int sn[8];
        bool val[8];
#pragma unroll
        for (int j = 0; j < 8; ++j) {
            int idx = i + j;
            val[j] = idx < end;
            sn[j] = __builtin_amdgcn_readfirstlane(srcs[val[j] ? idx : end - 1]);
        }
        float av[8];
        uint hb[8];
#pragma unroll
        for (int j = 0; j < 8; ++j)
            av[j] = *(const float*)(h2f8 + (size_t)sn[j] * 64 + 40);
#pragma unroll
        for (int j = 0; j < 8; ++j)
            hb[j] = h2f8[(size_t)sn[j] * 64 + col];
        float e[8];
#pragma unroll
        for (int j = 0; j < 8; ++j) {
            float a = av[j] + adn;
            e[j] = val[j] ? ((a > 0.f) ? a : 0.2f * a) : -INFINITY;
        }
        float mn = m;
#pragma unroll
        for (int j = 0; j < 8; ++j) mn = fmaxf(mn, e[j]);
        float corr = __expf(m - mn);
        float p[8];
#pragma unroll
        for (int j = 0; j < 8; ++j) p[j] = __expf(e[j] - mn);
        float ps = 0.f, pa = 0.f;
#pragma unroll
        for (int j = 0; j < 8; ++j) { ps += p[j]; pa += p[j] * fp8tof(hb[j]); }
        s = s * corr + ps;
        acc = acc * corr + pa;
        m = mn;
    }

    float val0 = acc / (s + 1e-16f) + (live ? b2[lane] : 0.f);
    float vmax = live ? val0 : -INFINITY;
#pragma unroll
    for (int msk = 1; msk < 64; msk <<= 1) vmax = fmaxf(vmax, __shfl_xor(vmax, msk, 64));
    float ex = live ? __expf(val0 - vmax) : 0.f;
#pragma unroll
    for (int msk = 1; msk < 64; msk <<= 1) ex += __shfl_xor(ex, msk, 64);
    float res = val0 - vmax - __logf(ex);
    if (live) out[(size_t)wid * NCLASS + lane] = res;
}

// ---------------- launch ----------------
extern "C" void kernel_launch(void* const* d_in, const int* in_sizes, int n_in,
                              void* d_out, int out_size, void* d_ws, size_t ws_size,
                              hipStream_t stream) {
    const float* x    = (const float*)d_in[0];
    const int*   ei   = (const int*)  d_in[1];
    const float* W1   = (const float*)d_in[2];
    const float* attS = (const float*)d_in[3];
    const float* attD = (const float*)d_in[4];
    const float* b1   = (const float*)d_in[5];
    const float* W2   = (const float*)d_in[6];
    const float* a2sw = (const float*)d_in[7];
    const float* a2dw = (const float*)d_in[8];
    const float* b2   = (const float*)d_in[9];

    int n = in_sizes[0] / NFEAT;
    int E = in_sizes[1] / 2;
    const int* srcE = ei;
    const int* dstE = ei + E;
    int nb = (n + 255) / 256;
    int mblocks = (n + 63) / 64;

    char* p = (char*)d_ws;
    auto alloc = [&](size_t bytes) {
        char* r = p;
        p += (bytes + 255) & ~(size_t)255;
        return r;
    };
    uchar*  h1f8 = (uchar*)alloc((size_t)n * HC);
    ushort* hgb  = (ushort*)alloc((size_t)n * HC * 2);
    uchar*  h2f8 = (uchar*)alloc((size_t)n * 64);
    ushort* Wb1  = (ushort*)alloc((size_t)17 * 4 * 64 * 8 * 2);
    ushort* Wb2  = (ushort*)alloc((size_t)3 * 8 * 64 * 8 * 2);
    float* a1x = (float*)alloc((size_t)n * 16 * 4);
    int* deg  = (int*)alloc((size_t)n * 4);
    int* rank = (int*)alloc((size_t)E * 4);
    int* bsum = (int*)alloc((size_t)nb * 4);
    int* ptr  = (int*)alloc((size_t)(n + 1) * 4);
    int* srcs = (int*)alloc((size_t)(E + n) * 4);

    int tot = E + n;
    int histb = (E + 256 * HU - 1) / (256 * HU);
    int scb = (tot + 256 * SU - 1) / (256 * SU);
    hipMemsetAsync(deg, 0, (size_t)n * 4, stream);
    k_hist_prep<<<PREPB + histb, 256, 0, stream>>>(dstE, E, deg, rank,
                                                   W1, attS, attD, W2, a2sw, a2dw,
                                                   Wb1, Wb2);
    k_blocksum<<<nb, 256, 0, stream>>>(deg, n, bsum);
    k_mkptr<<<nb, 256, 0, stream>>>(deg, bsum, n, ptr);

    // scatter + gemm1 fused (independent work, co-resident block ranges)
    k_scatter_gemm1<<<scb + mblocks, 256, 0, stream>>>(
        srcE, dstE, rank, ptr, E, n, srcs, scb, x, Wb1, h1f8, a1x);

    k_agg1<<<(n + 3) / 4, 256, 0, stream>>>((const uint*)h1f8, a1x, b1,
                                            ptr, srcs, n, hgb);
    k_gemm2<<<(n + 63) / 64, 256, 0, stream>>>(hgb, Wb2, n, h2f8);
    k_agg2<<<(n + 3) / 4, 256, 0, stream>>>(h2f8, b2, ptr, srcs, n, (float*)d_out);
}